// Round 1
// baseline (1429.742 us; speedup 1.0000x reference)
//
#include <hip/hip_runtime.h>
#include <math.h>

#define NH_ 8
#define D_ 256
#define NK_ 18
#define NQ_ 100
#define BS_ 8
#define LQ_ 1800          // NQ*NK
#define LEN_MEM_ 11253
#define NTOK_ 14400       // NQ*BS*NK

// ---------------- elementwise add (c = a + b), float4 ----------------
__global__ void add_kernel(const float* __restrict__ a, const float* __restrict__ b,
                           float* __restrict__ c, int n4) {
    int i = blockIdx.x * blockDim.x + threadIdx.x;
    if (i < n4) {
        float4 av = ((const float4*)a)[i];
        float4 bv = ((const float4*)b)[i];
        float4 cv;
        cv.x = av.x + bv.x; cv.y = av.y + bv.y; cv.z = av.z + bv.z; cv.w = av.w + bv.w;
        ((float4*)c)[i] = cv;
    }
}

// ---------------- generic linear: C[m,n] = A[m,:] . W[n,:] + bias[n] ----------------
// MODE 0: identity rows.
// MODE 1: value projection. A row gr = m*BS+b (memory layout), output row = b*LEN_MEM+m, zero if mask.
// MODE 2: msda q projection. Output row gr = b*LQ+lq; input row = q*BS*NK + b*NK + k (t3 layout).
// MODE 3: msda out projection. Input row gr = b*LQ+lq; output row = q*BS*NK + b*NK + k.
#define BM 64
#define BN 64
#define BK 16

template<int MODE, bool RELU>
__global__ __launch_bounds__(256)
void linear_kernel(const float* __restrict__ A, const float* __restrict__ W,
                   const float* __restrict__ bias, float* __restrict__ C,
                   int M, int N, int K, const unsigned char* __restrict__ mask) {
    __shared__ float As[BK][BM + 1];
    __shared__ float Ws[BK][BN + 1];
    const int m0 = blockIdx.x * BM;
    const int n0 = blockIdx.y * BN;
    const int tid = threadIdx.x;
    const int tx = tid & 15, ty = tid >> 4;
    const int lr = tid >> 2;          // 0..63 tile row
    const int lc = (tid & 3) << 2;    // col chunk within BK
    float acc[4][4] = {};
    for (int k0 = 0; k0 < K; k0 += BK) {
        int gr = m0 + lr;
        float4 av = make_float4(0.f, 0.f, 0.f, 0.f);
        if (gr < M) {
            size_t arow = gr;
            if (MODE == 2) {
                int b = gr / LQ_; int lq = gr - b * LQ_;
                int q = lq / NK_; int k = lq - q * NK_;
                arow = (size_t)q * (BS_ * NK_) + b * NK_ + k;
            }
            av = *(const float4*)(A + arow * (size_t)K + k0 + lc);
        }
        As[lc + 0][lr] = av.x; As[lc + 1][lr] = av.y;
        As[lc + 2][lr] = av.z; As[lc + 3][lr] = av.w;
        float4 wv = *(const float4*)(W + (size_t)(n0 + lr) * K + k0 + lc);
        Ws[lc + 0][lr] = wv.x; Ws[lc + 1][lr] = wv.y;
        Ws[lc + 2][lr] = wv.z; Ws[lc + 3][lr] = wv.w;
        __syncthreads();
#pragma unroll
        for (int k = 0; k < BK; ++k) {
            float a[4], bvv[4];
#pragma unroll
            for (int i = 0; i < 4; ++i) a[i] = As[k][ty * 4 + i];
#pragma unroll
            for (int j = 0; j < 4; ++j) bvv[j] = Ws[k][tx * 4 + j];
#pragma unroll
            for (int i = 0; i < 4; ++i)
#pragma unroll
                for (int j = 0; j < 4; ++j) acc[i][j] += a[i] * bvv[j];
        }
        __syncthreads();
    }
#pragma unroll
    for (int i = 0; i < 4; ++i) {
        int gm = m0 + ty * 4 + i;
        if (gm >= M) continue;
        size_t orow = gm;
        bool zero = false;
        if (MODE == 1) {
            int m = gm / BS_; int b = gm - m * BS_;
            orow = (size_t)b * LEN_MEM_ + m;
            if (mask && mask[(size_t)b * LEN_MEM_ + m]) zero = true;
        } else if (MODE == 3) {
            int b = gm / LQ_; int lq = gm - b * LQ_;
            int q = lq / NK_; int k = lq - q * NK_;
            orow = (size_t)q * (BS_ * NK_) + b * NK_ + k;
        }
#pragma unroll
        for (int j = 0; j < 4; ++j) {
            int gn = n0 + tx * 4 + j;
            float v = acc[i][j] + bias[gn];
            if (RELU) v = fmaxf(v, 0.f);
            if (zero) v = 0.f;
            C[orow * (size_t)N + gn] = v;
        }
    }
}

// ---------------- multi-head attention over small sequences ----------------
// qkv: (NTOK, 768) rows in t layout; row for (group g, seq s) = g*rowStrideG + s*rowStrideS
// out: (NTOK, 256) same row layout, head h at cols h*32..h*32+31
template<int S>
__global__ __launch_bounds__(256)
void attn_kernel(const float* __restrict__ qkv, float* __restrict__ out,
                 int rowStrideG, int rowStrideS) {
    __shared__ float Qs[S][33], Ks[S][33], Vs[S][32], Sc[S][S + 1];
    const int g = blockIdx.x / NH_;
    const int h = blockIdx.x % NH_;
    const int tid = threadIdx.x;
    for (int idx = tid; idx < S * 32; idx += 256) {
        int s = idx >> 5, d = idx & 31;
        size_t base = (size_t)(g * rowStrideG + s * rowStrideS) * 768 + h * 32 + d;
        Qs[s][d] = qkv[base];
        Ks[s][d] = qkv[base + 256];
        Vs[s][d] = qkv[base + 512];
    }
    __syncthreads();
    for (int idx = tid; idx < S * S; idx += 256) {
        int i = idx / S, j = idx - i * S;
        float acc = 0.f;
#pragma unroll
        for (int d = 0; d < 32; ++d) acc += Qs[i][d] * Ks[j][d];
        Sc[i][j] = acc * 0.17677669529663687f;   // 1/sqrt(32)
    }
    __syncthreads();
    for (int i = tid; i < S; i += 256) {
        float m = -1e30f;
        for (int j = 0; j < S; ++j) m = fmaxf(m, Sc[i][j]);
        float sum = 0.f;
        for (int j = 0; j < S; ++j) { float e = expf(Sc[i][j] - m); Sc[i][j] = e; sum += e; }
        float inv = 1.f / sum;
        for (int j = 0; j < S; ++j) Sc[i][j] *= inv;
    }
    __syncthreads();
    for (int idx = tid; idx < S * 32; idx += 256) {
        int i = idx >> 5, d = idx & 31;
        float acc = 0.f;
        for (int j = 0; j < S; ++j) acc += Sc[i][j] * Vs[j][d];
        out[(size_t)(g * rowStrideG + i * rowStrideS) * 256 + h * 32 + d] = acc;
    }
}

// ---------------- fused residual + layernorm: out = LN(base + delta) ----------------
__global__ __launch_bounds__(256)
void addln_kernel(const float* __restrict__ base, const float* __restrict__ delta,
                  const float* __restrict__ gamma, const float* __restrict__ beta,
                  float* __restrict__ out, int M) {
    int row = blockIdx.x * 4 + (threadIdx.x >> 6);
    int lane = threadIdx.x & 63;
    if (row >= M) return;
    const float* pb = base + (size_t)row * 256;
    const float* pd = delta + (size_t)row * 256;
    float v[4]; float s = 0.f;
#pragma unroll
    for (int i = 0; i < 4; ++i) { int c = lane + i * 64; v[i] = pb[c] + pd[c]; s += v[i]; }
#pragma unroll
    for (int off = 32; off; off >>= 1) s += __shfl_xor(s, off);
    float mean = s * (1.f / 256.f);
    float var = 0.f;
#pragma unroll
    for (int i = 0; i < 4; ++i) { float d = v[i] - mean; var += d * d; }
#pragma unroll
    for (int off = 32; off; off >>= 1) var += __shfl_xor(var, off);
    var *= (1.f / 256.f);
    float rstd = rsqrtf(var + 1e-5f);
#pragma unroll
    for (int i = 0; i < 4; ++i) {
        int c = lane + i * 64;
        out[(size_t)row * 256 + c] = (v[i] - mean) * rstd * gamma[c] + beta[c];
    }
}

// ---------------- MSDeformAttn sampling ----------------
// offb: (BS, LQ, 256) cols = h*32 + (lvl*4+p)*2 + {x,y}
// awb:  (BS, LQ, 128) cols = h*16 + lvl*4 + p (pre-softmax logits)
// value:(BS, LEN_MEM, NH, 32)
// refp: (LQ, BS, NL, 2)
// outb: (BS, LQ, 256) cols = h*32 + d
__global__ __launch_bounds__(256)
void msda_sample_kernel(const float* __restrict__ offb, const float* __restrict__ awb,
                        const float* __restrict__ value, const float* __restrict__ refp,
                        const int* __restrict__ spatial, const int* __restrict__ lsi,
                        float* __restrict__ outb) {
    int unit = blockIdx.x * 8 + (threadIdx.x >> 5);   // (b, lq, h)
    int lane = threadIdx.x & 31;                      // d
    int h = unit & 7;
    int t = unit >> 3;
    int lq = t % LQ_;
    int b = t / LQ_;

    const float* awp = awb + ((size_t)b * LQ_ + lq) * 128 + h * 16;
    float w[16];
    float m = -1e30f;
#pragma unroll
    for (int p = 0; p < 16; ++p) { w[p] = awp[p]; m = fmaxf(m, w[p]); }
    float sum = 0.f;
#pragma unroll
    for (int p = 0; p < 16; ++p) { w[p] = expf(w[p] - m); sum += w[p]; }
    float inv = 1.f / sum;

    const float* offp = offb + ((size_t)b * LQ_ + lq) * 256 + h * 32;
    float acc = 0.f;
#pragma unroll
    for (int lvl = 0; lvl < 4; ++lvl) {
        int H = spatial[lvl * 2], W = spatial[lvl * 2 + 1];
        int st = lsi[lvl];
        float rpx = refp[(((size_t)lq * BS_ + b) * 4 + lvl) * 2 + 0];
        float rpy = refp[(((size_t)lq * BS_ + b) * 4 + lvl) * 2 + 1];
        float fW = (float)W, fH = (float)H;
        const float* vb = value + ((size_t)b * LEN_MEM_ + st) * 256 + h * 32 + lane;
#pragma unroll
        for (int p = 0; p < 4; ++p) {
            float ox = offp[(lvl * 4 + p) * 2 + 0];
            float oy = offp[(lvl * 4 + p) * 2 + 1];
            float x = (rpx + ox / fW) * fW - 0.5f;
            float y = (rpy + oy / fH) * fH - 0.5f;
            float x0f = floorf(x), y0f = floorf(y);
            float lx = x - x0f, ly = y - y0f;
            int x0 = (int)x0f, y0 = (int)y0f;
            float wp = w[lvl * 4 + p] * inv;
            bool vx0 = (x0 >= 0) && (x0 < W);
            bool vx1 = (x0 + 1 >= 0) && (x0 + 1 < W);
            bool vy0 = (y0 >= 0) && (y0 < H);
            bool vy1 = (y0 + 1 >= 0) && (y0 + 1 < H);
            float c00 = 0.f, c10 = 0.f, c01 = 0.f, c11 = 0.f;
            if (vx0 && vy0) c00 = vb[((size_t)y0 * W + x0) * 256];
            if (vx1 && vy0) c10 = vb[((size_t)y0 * W + x0 + 1) * 256];
            if (vx0 && vy1) c01 = vb[((size_t)(y0 + 1) * W + x0) * 256];
            if (vx1 && vy1) c11 = vb[((size_t)(y0 + 1) * W + x0 + 1) * 256];
            acc += wp * ((1.f - lx) * (1.f - ly) * c00 + lx * (1.f - ly) * c10 +
                         (1.f - lx) * ly * c01 + lx * ly * c11);
        }
    }
    outb[((size_t)b * LQ_ + lq) * 256 + h * 32 + lane] = acc;
}

extern "C" void kernel_launch(void* const* d_in, const int* in_sizes, int n_in,
                              void* d_out, int out_size, void* d_ws, size_t ws_size,
                              hipStream_t stream) {
    const float* tgt     = (const float*)d_in[0];
    const float* pos     = (const float*)d_in[1];
    const float* refp    = (const float*)d_in[2];
    const float* memory  = (const float*)d_in[3];
    const float* w_in_w  = (const float*)d_in[4];
    const float* w_in_b  = (const float*)d_in[5];
    const float* w_out_w = (const float*)d_in[6];
    const float* w_out_b = (const float*)d_in[7];
    const float* a_in_w  = (const float*)d_in[8];
    const float* a_in_b  = (const float*)d_in[9];
    const float* a_out_w = (const float*)d_in[10];
    const float* a_out_b = (const float*)d_in[11];
    const float* off_w   = (const float*)d_in[12];
    const float* off_b   = (const float*)d_in[13];
    const float* aw_w    = (const float*)d_in[14];
    const float* aw_b    = (const float*)d_in[15];
    const float* val_w   = (const float*)d_in[16];
    const float* val_b   = (const float*)d_in[17];
    const float* outp_w  = (const float*)d_in[18];
    const float* outp_b  = (const float*)d_in[19];
    const float* wn_g    = (const float*)d_in[20];
    const float* wn_b    = (const float*)d_in[21];
    const float* an_g    = (const float*)d_in[22];
    const float* an_b    = (const float*)d_in[23];
    const float* n1_g    = (const float*)d_in[24];
    const float* n1_b    = (const float*)d_in[25];
    const float* n2_g    = (const float*)d_in[26];
    const float* n2_b    = (const float*)d_in[27];
    const float* l1_w    = (const float*)d_in[28];
    const float* l1_b    = (const float*)d_in[29];
    const float* l2_w    = (const float*)d_in[30];
    const float* l2_b    = (const float*)d_in[31];
    const int*   spatial = (const int*)d_in[32];
    const int*   lsi     = (const int*)d_in[33];
    const unsigned char* pmask = (const unsigned char*)d_in[34];
    float* out = (float*)d_out;
    float* ws  = (float*)d_ws;

    // workspace layout (floats)
    float* T   = ws;                    // 3,686,400   evolving t
    float* B   = T + 3686400;           // 14,745,600  qkv / ffn hidden
    float* CB  = B + 14745600;          // 3,686,400   attn out / sampled
    float* VAL = CB + 3686400;          // 23,046,144  msda value
    float* OFF = VAL + 23046144;        // 3,686,400   linear outs / offsets
    float* AW  = OFF + 3686400;         // 1,843,200   aw logits

    const int n4 = NTOK_ * 256 / 4;     // 921600

    // 1. T = tgt + pos
    add_kernel<<<n4 / 256, 256, 0, stream>>>(tgt, pos, T, n4);
    // 2. QKV for within-group MHA
    linear_kernel<0, false><<<dim3(225, 12), 256, 0, stream>>>(T, w_in_w, w_in_b, B, NTOK_, 768, 256, nullptr);
    // 3. attention over nk=18, groups g=q*BS+b (800), row = g*18 + s
    attn_kernel<18><<<800 * NH_, 256, 0, stream>>>(B, CB, 18, 1);
    // 4. out projection -> OFF
    linear_kernel<0, false><<<dim3(225, 4), 256, 0, stream>>>(CB, w_out_w, w_out_b, OFF, NTOK_, 256, 256, nullptr);
    // 5. T = LN(T + OFF, wn)
    addln_kernel<<<NTOK_ / 4, 256, 0, stream>>>(T, OFF, wn_g, wn_b, T, NTOK_);
    // 6. QKV for across-group MHA
    linear_kernel<0, false><<<dim3(225, 12), 256, 0, stream>>>(T, a_in_w, a_in_b, B, NTOK_, 768, 256, nullptr);
    // 7. attention over nq=100, groups b2=b*NK+k (144), row = s*144 + b2
    attn_kernel<100><<<144 * NH_, 256, 0, stream>>>(B, CB, 1, 144);
    // 8. out projection -> OFF
    linear_kernel<0, false><<<dim3(225, 4), 256, 0, stream>>>(CB, a_out_w, a_out_b, OFF, NTOK_, 256, 256, nullptr);
    // 9. T = LN(T + OFF, an)
    addln_kernel<<<NTOK_ / 4, 256, 0, stream>>>(T, OFF, an_g, an_b, T, NTOK_);
    // 10. T += pos   (t3)
    add_kernel<<<n4 / 256, 256, 0, stream>>>(T, pos, T, n4);
    // 11. value projection (M = 90024), output in (b, m) order, masked
    linear_kernel<1, false><<<dim3(1407, 4), 256, 0, stream>>>(memory, val_w, val_b, VAL, 90024, 256, 256, pmask);
    // 12. offsets projection (rows in (b,lq) order)
    linear_kernel<2, false><<<dim3(225, 4), 256, 0, stream>>>(T, off_w, off_b, OFF, NTOK_, 256, 256, nullptr);
    // 13. attention-weight logits
    linear_kernel<2, false><<<dim3(225, 2), 256, 0, stream>>>(T, aw_w, aw_b, AW, NTOK_, 128, 256, nullptr);
    // 14. bilinear sampling -> CB (rows (b,lq))
    msda_sample_kernel<<<NTOK_, 256, 0, stream>>>(OFF, AW, VAL, refp, spatial, lsi, CB);
    // 15. msda output projection, rows permuted back to (q,b,k) -> OFF
    linear_kernel<3, false><<<dim3(225, 4), 256, 0, stream>>>(CB, outp_w, outp_b, OFF, NTOK_, 256, 256, nullptr);
    // 16. T = LN(T + OFF, n1)   (t4)
    addln_kernel<<<NTOK_ / 4, 256, 0, stream>>>(T, OFF, n1_g, n1_b, T, NTOK_);
    // 17. FFN up + ReLU
    linear_kernel<0, true><<<dim3(225, 16), 256, 0, stream>>>(T, l1_w, l1_b, B, NTOK_, 1024, 256, nullptr);
    // 18. FFN down
    linear_kernel<0, false><<<dim3(225, 4), 256, 0, stream>>>(B, l2_w, l2_b, OFF, NTOK_, 256, 1024, nullptr);
    // 19. out = LN(T + OFF, n2)
    addln_kernel<<<NTOK_ / 4, 256, 0, stream>>>(T, OFF, n2_g, n2_b, out, NTOK_);
}

// Round 2
// 479.361 us; speedup vs baseline: 2.9826x; 2.9826x over previous
//
#include <hip/hip_runtime.h>
#include <math.h>

#define NH_ 8
#define D_ 256
#define NK_ 18
#define NQ_ 100
#define BS_ 8
#define LQ_ 1800          // NQ*NK
#define LEN_MEM_ 11253
#define NTOK_ 14400       // NQ*BS*NK

typedef short bf16x8 __attribute__((ext_vector_type(8)));
typedef float f32x4 __attribute__((ext_vector_type(4)));
typedef unsigned short ushort;

__device__ inline ushort f2bf(float f) {
    unsigned int u = __builtin_bit_cast(unsigned int, f);
    unsigned int r = (u + 0x7fffu + ((u >> 16) & 1u)) >> 16;
    return (ushort)r;
}
__device__ inline float bf2f(unsigned int u16) {
    unsigned int i = u16 << 16;
    return __builtin_bit_cast(float, i);
}

// ---------------- weight convert: 10 f32 tensors -> packed bf16 arena ----------------
__global__ __launch_bounds__(256)
void wcvt_kernel(const float* s0, const float* s1, const float* s2, const float* s3,
                 const float* s4, const float* s5, const float* s6, const float* s7,
                 const float* s8, const float* s9, ushort* dst) {
    const int sizes[10] = {196608,65536,196608,65536,65536,32768,65536,65536,262144,262144};
    const int offs[10]  = {0,196608,262144,458752,524288,589824,622592,688128,753664,1015808};
    int ti = blockIdx.y;
    const float* s;
    switch (ti) {
        case 0: s = s0; break; case 1: s = s1; break; case 2: s = s2; break;
        case 3: s = s3; break; case 4: s = s4; break; case 5: s = s5; break;
        case 6: s = s6; break; case 7: s = s7; break; case 8: s = s8; break;
        default: s = s9; break;
    }
    int n = sizes[ti];
    int i = (blockIdx.x * 256 + threadIdx.x) * 8;
    if (i >= n) return;
    ushort* d = dst + offs[ti] + i;
    float4 f0 = *(const float4*)(s + i);
    float4 f1 = *(const float4*)(s + i + 4);
    int4 val;
    val.x = (int)f2bf(f0.x) | ((int)f2bf(f0.y) << 16);
    val.y = (int)f2bf(f0.z) | ((int)f2bf(f0.w) << 16);
    val.z = (int)f2bf(f1.x) | ((int)f2bf(f1.y) << 16);
    val.w = (int)f2bf(f1.z) | ((int)f2bf(f1.w) << 16);
    *(int4*)d = val;
}

// ---------------- c = a + b, f32 out + bf16 shadow ----------------
__global__ __launch_bounds__(256)
void addcvt_kernel(const float* __restrict__ a, const float* __restrict__ b,
                   float* __restrict__ c, ushort* __restrict__ cbf, int n4) {
    int i = blockIdx.x * blockDim.x + threadIdx.x;
    if (i >= n4) return;
    float4 av = ((const float4*)a)[i];
    float4 bv = ((const float4*)b)[i];
    float4 cv;
    cv.x = av.x + bv.x; cv.y = av.y + bv.y; cv.z = av.z + bv.z; cv.w = av.w + bv.w;
    ((float4*)c)[i] = cv;
    uint2 p;
    p.x = (unsigned int)f2bf(cv.x) | ((unsigned int)f2bf(cv.y) << 16);
    p.y = (unsigned int)f2bf(cv.z) | ((unsigned int)f2bf(cv.w) << 16);
    *(uint2*)(cbf + (size_t)i * 4) = p;
}

// ---------------- MFMA bf16 GEMM: C[m,n] = A[m,:] . W[n,:] + bias[n] ----------------
// A: (M,K) bf16 (or f32 if A_F32, converted during staging). W: (N,K) bf16.
// MODE 0: identity rows.
// MODE 1: value projection. Output row gm = b*LEN_MEM+m; input row = m*BS+b; mask-zero.
// MODE 2: input row permute (q,b,k) -> output rows in (b,lq) order.
// MODE 3: input rows (b,lq), output rows (q,b,k).
template<int MODE, bool RELU, bool A_F32, bool OUT_BF16>
__global__ __launch_bounds__(256)
void gemm_kernel(const void* __restrict__ Av, const ushort* __restrict__ W,
                 const float* __restrict__ bias, void* __restrict__ Cv,
                 int M, int N, int K, const unsigned char* __restrict__ mask) {
    __shared__ ushort As[128 * 40];
    __shared__ ushort Bs[128 * 40];
    const int m0 = blockIdx.x * 128, n0 = blockIdx.y * 128;
    const int tid = threadIdx.x;
    const int w = tid >> 6, lane = tid & 63;
    const int wr = w >> 1, wc = w & 1;
    const int fr = lane & 15, hi = lane >> 4;
    f32x4 acc[4][4];
#pragma unroll
    for (int i = 0; i < 4; ++i)
#pragma unroll
        for (int j = 0; j < 4; ++j) acc[i][j] = f32x4{0.f, 0.f, 0.f, 0.f};

    for (int k0 = 0; k0 < K; k0 += 32) {
#pragma unroll
        for (int cc = 0; cc < 2; ++cc) {
            int c = tid + cc * 256;
            int row = c >> 2, kq = c & 3;
            int gr = m0 + row;
            int4 val = make_int4(0, 0, 0, 0);
            if (gr < M) {
                long arow;
                if (MODE == 1) {
                    int b = gr / LEN_MEM_; int m = gr - b * LEN_MEM_;
                    arow = (long)m * BS_ + b;
                } else if (MODE == 2) {
                    int b = gr / LQ_; int lq = gr - b * LQ_;
                    int q = lq / NK_; int kk = lq - q * NK_;
                    arow = (long)q * (BS_ * NK_) + b * NK_ + kk;
                } else {
                    arow = gr;
                }
                if (A_F32) {
                    const float* ap = (const float*)Av + arow * (long)K + k0 + kq * 8;
                    float4 f0 = *(const float4*)ap;
                    float4 f1 = *(const float4*)(ap + 4);
                    val.x = (int)f2bf(f0.x) | ((int)f2bf(f0.y) << 16);
                    val.y = (int)f2bf(f0.z) | ((int)f2bf(f0.w) << 16);
                    val.z = (int)f2bf(f1.x) | ((int)f2bf(f1.y) << 16);
                    val.w = (int)f2bf(f1.z) | ((int)f2bf(f1.w) << 16);
                } else {
                    val = *(const int4*)((const ushort*)Av + arow * (long)K + k0 + kq * 8);
                }
            }
            *(int4*)(As + row * 40 + kq * 8) = val;
        }
#pragma unroll
        for (int cc = 0; cc < 2; ++cc) {
            int c = tid + cc * 256;
            int row = c >> 2, kq = c & 3;
            *(int4*)(Bs + row * 40 + kq * 8) =
                *(const int4*)(W + (long)(n0 + row) * K + k0 + kq * 8);
        }
        __syncthreads();
        bf16x8 af[4], bfr[4];
#pragma unroll
        for (int i = 0; i < 4; ++i)
            af[i] = *(const bf16x8*)(As + (wr * 64 + i * 16 + fr) * 40 + hi * 8);
#pragma unroll
        for (int j = 0; j < 4; ++j)
            bfr[j] = *(const bf16x8*)(Bs + (wc * 64 + j * 16 + fr) * 40 + hi * 8);
#pragma unroll
        for (int i = 0; i < 4; ++i)
#pragma unroll
            for (int j = 0; j < 4; ++j)
                acc[i][j] = __builtin_amdgcn_mfma_f32_16x16x32_bf16(af[i], bfr[j], acc[i][j], 0, 0, 0);
        __syncthreads();
    }

#pragma unroll
    for (int i = 0; i < 4; ++i) {
#pragma unroll
        for (int r = 0; r < 4; ++r) {
            int gm = m0 + wr * 64 + i * 16 + hi * 4 + r;
            if (gm >= M) continue;
            long orow = gm;
            bool zero = false;
            if (MODE == 1) {
                if (mask && mask[gm]) zero = true;
            } else if (MODE == 3) {
                int b = gm / LQ_; int lq = gm - b * LQ_;
                int q = lq / NK_; int kk = lq - q * NK_;
                orow = (long)q * (BS_ * NK_) + b * NK_ + kk;
            }
#pragma unroll
            for (int j = 0; j < 4; ++j) {
                int gn = n0 + wc * 64 + j * 16 + fr;
                float v = acc[i][j][r] + bias[gn];
                if (RELU) v = fmaxf(v, 0.f);
                if (zero) v = 0.f;
                if (OUT_BF16) ((ushort*)Cv)[orow * (long)N + gn] = f2bf(v);
                else ((float*)Cv)[orow * (long)N + gn] = v;
            }
        }
    }
}

// ---------------- multi-head attention over small sequences (f32 in, bf16 out) ----------------
template<int S>
__global__ __launch_bounds__(256)
void attn_kernel(const float* __restrict__ qkv, ushort* __restrict__ out,
                 int rowStrideG, int rowStrideS) {
    __shared__ float Qs[S][33], Ks[S][33], Vs[S][32], Sc[S][S + 1];
    const int g = blockIdx.x / NH_;
    const int h = blockIdx.x % NH_;
    const int tid = threadIdx.x;
    for (int idx = tid; idx < S * 32; idx += 256) {
        int s = idx >> 5, d = idx & 31;
        size_t base = (size_t)(g * rowStrideG + s * rowStrideS) * 768 + h * 32 + d;
        Qs[s][d] = qkv[base];
        Ks[s][d] = qkv[base + 256];
        Vs[s][d] = qkv[base + 512];
    }
    __syncthreads();
    for (int idx = tid; idx < S * S; idx += 256) {
        int i = idx / S, j = idx - i * S;
        float acc = 0.f;
#pragma unroll
        for (int d = 0; d < 32; ++d) acc += Qs[i][d] * Ks[j][d];
        Sc[i][j] = acc * 0.17677669529663687f;
    }
    __syncthreads();
    for (int i = tid; i < S; i += 256) {
        float m = -1e30f;
        for (int j = 0; j < S; ++j) m = fmaxf(m, Sc[i][j]);
        float sum = 0.f;
        for (int j = 0; j < S; ++j) { float e = expf(Sc[i][j] - m); Sc[i][j] = e; sum += e; }
        float inv = 1.f / sum;
        for (int j = 0; j < S; ++j) Sc[i][j] *= inv;
    }
    __syncthreads();
    for (int idx = tid; idx < S * 32; idx += 256) {
        int i = idx >> 5, d = idx & 31;
        float acc = 0.f;
        for (int j = 0; j < S; ++j) acc += Sc[i][j] * Vs[j][d];
        out[(size_t)(g * rowStrideG + i * rowStrideS) * 256 + h * 32 + d] = f2bf(acc);
    }
}

// ---------------- fused residual + layernorm, f32 out + optional bf16 shadow ----------------
__global__ __launch_bounds__(256)
void addln_kernel(const float* __restrict__ base, const float* __restrict__ delta,
                  const float* __restrict__ gamma, const float* __restrict__ beta,
                  float* __restrict__ out, ushort* __restrict__ obf, int M) {
    int row = blockIdx.x * 4 + (threadIdx.x >> 6);
    int lane = threadIdx.x & 63;
    if (row >= M) return;
    const float* pb = base + (size_t)row * 256;
    const float* pd = delta + (size_t)row * 256;
    float v[4]; float s = 0.f;
#pragma unroll
    for (int i = 0; i < 4; ++i) { int c = lane + i * 64; v[i] = pb[c] + pd[c]; s += v[i]; }
#pragma unroll
    for (int off = 32; off; off >>= 1) s += __shfl_xor(s, off);
    float mean = s * (1.f / 256.f);
    float var = 0.f;
#pragma unroll
    for (int i = 0; i < 4; ++i) { float d = v[i] - mean; var += d * d; }
#pragma unroll
    for (int off = 32; off; off >>= 1) var += __shfl_xor(var, off);
    var *= (1.f / 256.f);
    float rstd = rsqrtf(var + 1e-5f);
#pragma unroll
    for (int i = 0; i < 4; ++i) {
        int c = lane + i * 64;
        float o = (v[i] - mean) * rstd * gamma[c] + beta[c];
        out[(size_t)row * 256 + c] = o;
        if (obf) obf[(size_t)row * 256 + c] = f2bf(o);
    }
}

// ---------------- attention-weight softmax (one thread per (b,lq,h)) ----------------
__global__ __launch_bounds__(256)
void awsm_kernel(const float* __restrict__ aw, float* __restrict__ awn) {
    int u = blockIdx.x * 256 + threadIdx.x;
    if (u >= NTOK_ * 8) return;
    int row = u >> 3, h = u & 7;
    const float* p = aw + (size_t)row * 128 + h * 16;
    float w[16], m = -1e30f;
#pragma unroll
    for (int i = 0; i < 16; ++i) { w[i] = p[i]; m = fmaxf(m, w[i]); }
    float sum = 0.f;
#pragma unroll
    for (int i = 0; i < 16; ++i) { w[i] = expf(w[i] - m); sum += w[i]; }
    float inv = 1.f / sum;
    float* o = awn + (size_t)u * 16;
#pragma unroll
    for (int i = 0; i < 16; ++i) o[i] = w[i] * inv;
}

// ---------------- MSDeformAttn bilinear sampling (bf16 value, bf16 out) ----------------
// 16 lanes per (b,lq,h) unit; each lane handles 2 packed channels.
__global__ __launch_bounds__(256)
void msda_kernel(const float* __restrict__ offb, const float* __restrict__ awn,
                 const ushort* __restrict__ val, const float* __restrict__ refp,
                 const int* __restrict__ spatial, const int* __restrict__ lsi,
                 ushort* __restrict__ samp) {
    int unit = blockIdx.x * 16 + (threadIdx.x >> 4);
    int lane = threadIdx.x & 15;
    int h = unit & 7;
    int t = unit >> 3;
    int lq = t % LQ_;
    int b = t / LQ_;
    const float* offp = offb + ((size_t)b * LQ_ + lq) * 256 + h * 32;
    const float* wp = awn + (size_t)unit * 16;
    float acc0 = 0.f, acc1 = 0.f;
#pragma unroll
    for (int lvl = 0; lvl < 4; ++lvl) {
        int H = spatial[lvl * 2], W = spatial[lvl * 2 + 1];
        int st = lsi[lvl];
        float rpx = refp[(((size_t)lq * BS_ + b) * 4 + lvl) * 2 + 0];
        float rpy = refp[(((size_t)lq * BS_ + b) * 4 + lvl) * 2 + 1];
        const ushort* vb = val + ((size_t)b * LEN_MEM_ + st) * 256 + h * 32 + lane * 2;
        float fW = (float)W, fH = (float)H;
#pragma unroll
        for (int p = 0; p < 4; ++p) {
            float ox = offp[(lvl * 4 + p) * 2 + 0];
            float oy = offp[(lvl * 4 + p) * 2 + 1];
            float x = rpx * fW + ox - 0.5f;
            float y = rpy * fH + oy - 0.5f;
            float x0f = floorf(x), y0f = floorf(y);
            float lx = x - x0f, ly = y - y0f;
            int x0 = (int)x0f, y0 = (int)y0f;
            int xc0 = min(max(x0, 0), W - 1), xc1 = min(max(x0 + 1, 0), W - 1);
            int yc0 = min(max(y0, 0), H - 1), yc1 = min(max(y0 + 1, 0), H - 1);
            float vx0 = (x0 >= 0 && x0 < W) ? 1.f : 0.f;
            float vx1 = (x0 >= -1 && x0 + 1 < W) ? 1.f : 0.f;
            float vy0 = (y0 >= 0 && y0 < H) ? 1.f : 0.f;
            float vy1 = (y0 >= -1 && y0 + 1 < H) ? 1.f : 0.f;
            float wpt = wp[lvl * 4 + p];
            float w00 = wpt * (1.f - lx) * (1.f - ly) * vx0 * vy0;
            float w10 = wpt * lx * (1.f - ly) * vx1 * vy0;
            float w01 = wpt * (1.f - lx) * ly * vx0 * vy1;
            float w11 = wpt * lx * ly * vx1 * vy1;
            unsigned int u00 = *(const unsigned int*)(vb + ((size_t)yc0 * W + xc0) * 256);
            unsigned int u10 = *(const unsigned int*)(vb + ((size_t)yc0 * W + xc1) * 256);
            unsigned int u01 = *(const unsigned int*)(vb + ((size_t)yc1 * W + xc0) * 256);
            unsigned int u11 = *(const unsigned int*)(vb + ((size_t)yc1 * W + xc1) * 256);
            acc0 += w00 * bf2f(u00 & 0xffff) + w10 * bf2f(u10 & 0xffff)
                  + w01 * bf2f(u01 & 0xffff) + w11 * bf2f(u11 & 0xffff);
            acc1 += w00 * bf2f(u00 >> 16) + w10 * bf2f(u10 >> 16)
                  + w01 * bf2f(u01 >> 16) + w11 * bf2f(u11 >> 16);
        }
    }
    size_t o = ((size_t)b * LQ_ + lq) * 256 + h * 32 + lane * 2;
    unsigned int pack = (unsigned int)f2bf(acc0) | ((unsigned int)f2bf(acc1) << 16);
    *(unsigned int*)(samp + o) = pack;
}

extern "C" void kernel_launch(void* const* d_in, const int* in_sizes, int n_in,
                              void* d_out, int out_size, void* d_ws, size_t ws_size,
                              hipStream_t stream) {
    const float* tgt     = (const float*)d_in[0];
    const float* pos     = (const float*)d_in[1];
    const float* refp    = (const float*)d_in[2];
    const float* memory  = (const float*)d_in[3];
    const float* w_in_w  = (const float*)d_in[4];
    const float* w_in_b  = (const float*)d_in[5];
    const float* w_out_w = (const float*)d_in[6];
    const float* w_out_b = (const float*)d_in[7];
    const float* a_in_w  = (const float*)d_in[8];
    const float* a_in_b  = (const float*)d_in[9];
    const float* a_out_w = (const float*)d_in[10];
    const float* a_out_b = (const float*)d_in[11];
    const float* off_w   = (const float*)d_in[12];
    const float* off_b   = (const float*)d_in[13];
    const float* aw_w    = (const float*)d_in[14];
    const float* aw_b    = (const float*)d_in[15];
    const float* val_w   = (const float*)d_in[16];
    const float* val_b   = (const float*)d_in[17];
    const float* outp_w  = (const float*)d_in[18];
    const float* outp_b  = (const float*)d_in[19];
    const float* wn_g    = (const float*)d_in[20];
    const float* wn_b    = (const float*)d_in[21];
    const float* an_g    = (const float*)d_in[22];
    const float* an_b    = (const float*)d_in[23];
    const float* n1_g    = (const float*)d_in[24];
    const float* n1_b    = (const float*)d_in[25];
    const float* n2_g    = (const float*)d_in[26];
    const float* n2_b    = (const float*)d_in[27];
    const float* l1_w    = (const float*)d_in[28];
    const float* l1_b    = (const float*)d_in[29];
    const float* l2_w    = (const float*)d_in[30];
    const float* l2_b    = (const float*)d_in[31];
    const int*   spatial = (const int*)d_in[32];
    const int*   lsi     = (const int*)d_in[33];
    const unsigned char* pmask = (const unsigned char*)d_in[34];
    float* out = (float*)d_out;
    float* ws  = (float*)d_ws;

    // workspace layout (float units)
    float*  T     = ws;                       // 3,686,400
    ushort* Tbf   = (ushort*)(T + 3686400);   // 1,843,200 f
    float*  B     = (float*)(Tbf) + 1843200;  // 11,059,200  (QKV f32)
    ushort* CBbf  = (ushort*)(B + 11059200);  // 1,843,200 f
    ushort* VALbf = (ushort*)((float*)CBbf + 1843200);  // 11,523,072 f
    float*  OFF   = (float*)VALbf + 11523072; // 3,686,400
    float*  AW    = OFF + 3686400;            // 1,843,200
    float*  AWn   = AW + 1843200;             // 1,843,200
    ushort* SAMPbf= (ushort*)(AWn + 1843200); // 1,843,200 f
    ushort* Hbf   = (ushort*)((float*)SAMPbf + 1843200); // 7,372,800 f
    ushort* WB    = (ushort*)((float*)Hbf + 7372800);    // 638,976 f

    // bf16 weight arena offsets
    ushort* WB_win  = WB + 0;
    ushort* WB_wout = WB + 196608;
    ushort* WB_ain  = WB + 262144;
    ushort* WB_aout = WB + 458752;
    ushort* WB_off  = WB + 524288;
    ushort* WB_aw   = WB + 589824;
    ushort* WB_val  = WB + 622592;
    ushort* WB_outp = WB + 688128;
    ushort* WB_l1   = WB + 753664;
    ushort* WB_l2   = WB + 1015808;

    const int n4 = NTOK_ * 256 / 4;           // 921600

    // 0. weights -> bf16
    wcvt_kernel<<<dim3(128, 10), 256, 0, stream>>>(
        w_in_w, w_out_w, a_in_w, a_out_w, off_w, aw_w, val_w, outp_w, l1_w, l2_w, WB);
    // 1. T = tgt + pos (+bf16)
    addcvt_kernel<<<n4 / 256, 256, 0, stream>>>(tgt, pos, T, Tbf, n4);
    // 2. QKV (within-group)
    gemm_kernel<0, false, false, false><<<dim3(113, 6), 256, 0, stream>>>(
        Tbf, WB_win, w_in_b, B, NTOK_, 768, 256, nullptr);
    // 3. attention over nk=18
    attn_kernel<18><<<800 * NH_, 256, 0, stream>>>(B, CBbf, 18, 1);
    // 4. out projection
    gemm_kernel<0, false, false, false><<<dim3(113, 2), 256, 0, stream>>>(
        CBbf, WB_wout, w_out_b, OFF, NTOK_, 256, 256, nullptr);
    // 5. T = LN(T+OFF, wn)
    addln_kernel<<<NTOK_ / 4, 256, 0, stream>>>(T, OFF, wn_g, wn_b, T, Tbf, NTOK_);
    // 6. QKV (across-group)
    gemm_kernel<0, false, false, false><<<dim3(113, 6), 256, 0, stream>>>(
        Tbf, WB_ain, a_in_b, B, NTOK_, 768, 256, nullptr);
    // 7. attention over nq=100
    attn_kernel<100><<<144 * NH_, 256, 0, stream>>>(B, CBbf, 1, 144);
    // 8. out projection
    gemm_kernel<0, false, false, false><<<dim3(113, 2), 256, 0, stream>>>(
        CBbf, WB_aout, a_out_b, OFF, NTOK_, 256, 256, nullptr);
    // 9. T = LN(T+OFF, an)
    addln_kernel<<<NTOK_ / 4, 256, 0, stream>>>(T, OFF, an_g, an_b, T, Tbf, NTOK_);
    // 10. T += pos (t3)
    addcvt_kernel<<<n4 / 256, 256, 0, stream>>>(T, pos, T, Tbf, n4);
    // 11. value projection (f32 memory in, bf16 out, masked) -> VALbf (b,m) order
    gemm_kernel<1, false, true, true><<<dim3(704, 2), 256, 0, stream>>>(
        memory, WB_val, val_b, VALbf, 90024, 256, 256, pmask);
    // 12. offsets projection (rows (b,lq))
    gemm_kernel<2, false, false, false><<<dim3(113, 2), 256, 0, stream>>>(
        Tbf, WB_off, off_b, OFF, NTOK_, 256, 256, nullptr);
    // 13. attention-weight logits
    gemm_kernel<2, false, false, false><<<dim3(113, 1), 256, 0, stream>>>(
        Tbf, WB_aw, aw_b, AW, NTOK_, 128, 256, nullptr);
    // 14. softmax over 16 points
    awsm_kernel<<<(NTOK_ * 8 + 255) / 256, 256, 0, stream>>>(AW, AWn);
    // 15. bilinear sampling
    msda_kernel<<<NTOK_ * 8 / 16, 256, 0, stream>>>(OFF, AWn, VALbf, refp, spatial, lsi, SAMPbf);
    // 16. msda output projection (rows back to (q,b,k))
    gemm_kernel<3, false, false, false><<<dim3(113, 2), 256, 0, stream>>>(
        SAMPbf, WB_outp, outp_b, OFF, NTOK_, 256, 256, nullptr);
    // 17. T = LN(T+OFF, n1)
    addln_kernel<<<NTOK_ / 4, 256, 0, stream>>>(T, OFF, n1_g, n1_b, T, Tbf, NTOK_);
    // 18. FFN up + ReLU (bf16 out)
    gemm_kernel<0, true, false, true><<<dim3(113, 8), 256, 0, stream>>>(
        Tbf, WB_l1, l1_b, Hbf, NTOK_, 1024, 256, nullptr);
    // 19. FFN down
    gemm_kernel<0, false, false, false><<<dim3(113, 2), 256, 0, stream>>>(
        Hbf, WB_l2, l2_b, OFF, NTOK_, 256, 1024, nullptr);
    // 20. out = LN(T+OFF, n2)
    addln_kernel<<<NTOK_ / 4, 256, 0, stream>>>(T, OFF, n2_g, n2_b, out, nullptr, NTOK_);
}

// Round 4
// 370.782 us; speedup vs baseline: 3.8560x; 1.2928x over previous
//
#include <hip/hip_runtime.h>
#include <math.h>

#define NH_ 8
#define D_ 256
#define NK_ 18
#define NQ_ 100
#define BS_ 8
#define LQ_ 1800          // NQ*NK
#define LEN_MEM_ 11253
#define NTOK_ 14400       // NQ*BS*NK

typedef short bf16x8 __attribute__((ext_vector_type(8)));
typedef float f32x4 __attribute__((ext_vector_type(4)));
typedef unsigned short ushort;

__device__ inline ushort f2bf(float f) {
    unsigned int u = __builtin_bit_cast(unsigned int, f);
    unsigned int r = (u + 0x7fffu + ((u >> 16) & 1u)) >> 16;
    return (ushort)r;
}
__device__ inline float bf2f(unsigned int u16) {
    unsigned int i = u16 << 16;
    return __builtin_bit_cast(float, i);
}

// ---------------- weight convert: 10 f32 tensors -> packed bf16 arena ----------------
__global__ __launch_bounds__(256)
void wcvt_kernel(const float* s0, const float* s1, const float* s2, const float* s3,
                 const float* s4, const float* s5, const float* s6, const float* s7,
                 const float* s8, const float* s9, ushort* dst) {
    const int sizes[10] = {196608,65536,196608,65536,65536,32768,65536,65536,262144,262144};
    const int offs[10]  = {0,196608,262144,458752,524288,589824,622592,688128,753664,1015808};
    int ti = blockIdx.y;
    const float* s;
    switch (ti) {
        case 0: s = s0; break; case 1: s = s1; break; case 2: s = s2; break;
        case 3: s = s3; break; case 4: s = s4; break; case 5: s = s5; break;
        case 6: s = s6; break; case 7: s = s7; break; case 8: s = s8; break;
        default: s = s9; break;
    }
    int n = sizes[ti];
    int i = (blockIdx.x * 256 + threadIdx.x) * 8;
    if (i >= n) return;
    ushort* d = dst + offs[ti] + i;
    float4 f0 = *(const float4*)(s + i);
    float4 f1 = *(const float4*)(s + i + 4);
    int4 val;
    val.x = (int)f2bf(f0.x) | ((int)f2bf(f0.y) << 16);
    val.y = (int)f2bf(f0.z) | ((int)f2bf(f0.w) << 16);
    val.z = (int)f2bf(f1.x) | ((int)f2bf(f1.y) << 16);
    val.w = (int)f2bf(f1.z) | ((int)f2bf(f1.w) << 16);
    *(int4*)d = val;
}

// ---------------- c = a + b, f32 out + bf16 shadow ----------------
__global__ __launch_bounds__(256)
void addcvt_kernel(const float* __restrict__ a, const float* __restrict__ b,
                   float* __restrict__ c, ushort* __restrict__ cbf, int n4) {
    int i = blockIdx.x * blockDim.x + threadIdx.x;
    if (i >= n4) return;
    float4 av = ((const float4*)a)[i];
    float4 bv = ((const float4*)b)[i];
    float4 cv;
    cv.x = av.x + bv.x; cv.y = av.y + bv.y; cv.z = av.z + bv.z; cv.w = av.w + bv.w;
    ((float4*)c)[i] = cv;
    uint2 p;
    p.x = (unsigned int)f2bf(cv.x) | ((unsigned int)f2bf(cv.y) << 16);
    p.y = (unsigned int)f2bf(cv.z) | ((unsigned int)f2bf(cv.w) << 16);
    *(uint2*)(cbf + (size_t)i * 4) = p;
}

// ---------------- MFMA bf16 GEMM: C[m,n] = A[m,:] . W[n,:] + bias[n] ----------------
template<int MODE, bool RELU, bool A_F32, bool OUT_BF16>
__global__ __launch_bounds__(256)
void gemm_kernel(const void* __restrict__ Av, const ushort* __restrict__ W,
                 const float* __restrict__ bias, void* __restrict__ Cv,
                 int M, int N, int K, const unsigned char* __restrict__ mask) {
    __shared__ ushort As[128 * 40];
    __shared__ ushort Bs[128 * 40];
    const int m0 = blockIdx.x * 128, n0 = blockIdx.y * 128;
    const int tid = threadIdx.x;
    const int w = tid >> 6, lane = tid & 63;
    const int wr = w >> 1, wc = w & 1;
    const int fr = lane & 15, hi = lane >> 4;
    f32x4 acc[4][4];
#pragma unroll
    for (int i = 0; i < 4; ++i)
#pragma unroll
        for (int j = 0; j < 4; ++j) acc[i][j] = f32x4{0.f, 0.f, 0.f, 0.f};

    for (int k0 = 0; k0 < K; k0 += 32) {
#pragma unroll
        for (int cc = 0; cc < 2; ++cc) {
            int c = tid + cc * 256;
            int row = c >> 2, kq = c & 3;
            int gr = m0 + row;
            int4 val = make_int4(0, 0, 0, 0);
            if (gr < M) {
                long arow;
                if (MODE == 1) {
                    int b = gr / LEN_MEM_; int m = gr - b * LEN_MEM_;
                    arow = (long)m * BS_ + b;
                } else if (MODE == 2) {
                    int b = gr / LQ_; int lq = gr - b * LQ_;
                    int q = lq / NK_; int kk = lq - q * NK_;
                    arow = (long)q * (BS_ * NK_) + b * NK_ + kk;
                } else {
                    arow = gr;
                }
                if (A_F32) {
                    const float* ap = (const float*)Av + arow * (long)K + k0 + kq * 8;
                    float4 f0 = *(const float4*)ap;
                    float4 f1 = *(const float4*)(ap + 4);
                    val.x = (int)f2bf(f0.x) | ((int)f2bf(f0.y) << 16);
                    val.y = (int)f2bf(f0.z) | ((int)f2bf(f0.w) << 16);
                    val.z = (int)f2bf(f1.x) | ((int)f2bf(f1.y) << 16);
                    val.w = (int)f2bf(f1.z) | ((int)f2bf(f1.w) << 16);
                } else {
                    val = *(const int4*)((const ushort*)Av + arow * (long)K + k0 + kq * 8);
                }
            }
            *(int4*)(As + row * 40 + kq * 8) = val;
        }
#pragma unroll
        for (int cc = 0; cc < 2; ++cc) {
            int c = tid + cc * 256;
            int row = c >> 2, kq = c & 3;
            *(int4*)(Bs + row * 40 + kq * 8) =
                *(const int4*)(W + (long)(n0 + row) * K + k0 + kq * 8);
        }
        __syncthreads();
        bf16x8 af[4], bfr[4];
#pragma unroll
        for (int i = 0; i < 4; ++i)
            af[i] = *(const bf16x8*)(As + (wr * 64 + i * 16 + fr) * 40 + hi * 8);
#pragma unroll
        for (int j = 0; j < 4; ++j)
            bfr[j] = *(const bf16x8*)(Bs + (wc * 64 + j * 16 + fr) * 40 + hi * 8);
#pragma unroll
        for (int i = 0; i < 4; ++i)
#pragma unroll
            for (int j = 0; j < 4; ++j)
                acc[i][j] = __builtin_amdgcn_mfma_f32_16x16x32_bf16(af[i], bfr[j], acc[i][j], 0, 0, 0);
        __syncthreads();
    }

#pragma unroll
    for (int i = 0; i < 4; ++i) {
#pragma unroll
        for (int r = 0; r < 4; ++r) {
            int gm = m0 + wr * 64 + i * 16 + hi * 4 + r;
            if (gm >= M) continue;
            long orow = gm;
            bool zero = false;
            if (MODE == 1) {
                if (mask && mask[gm]) zero = true;
            } else if (MODE == 3) {
                int b = gm / LQ_; int lq = gm - b * LQ_;
                int q = lq / NK_; int kk = lq - q * NK_;
                orow = (long)q * (BS_ * NK_) + b * NK_ + kk;
            }
#pragma unroll
            for (int j = 0; j < 4; ++j) {
                int gn = n0 + wc * 64 + j * 16 + fr;
                float v = acc[i][j][r] + bias[gn];
                if (RELU) v = fmaxf(v, 0.f);
                if (zero) v = 0.f;
                if (OUT_BF16) ((ushort*)Cv)[orow * (long)N + gn] = f2bf(v);
                else ((float*)Cv)[orow * (long)N + gn] = v;
            }
        }
    }
}

// ---------------- MFMA multi-head attention over small sequences ----------------
// qkv: (NTOK, 768) bf16, row for (group g, seq s) = g*rsG + s*rsS.
// Q at col h*32, K at 256+h*32, V at 512+h*32. out: (NTOK, 256) bf16, same rows.
// Block handles HPB heads of one group. SP = S padded to 16; SPk = SP padded to 32.
template<int S, int SP, int HPB>
__global__ __launch_bounds__(256)
void mattn_kernel(const ushort* __restrict__ qkv, ushort* __restrict__ outb,
                  int rsG, int rsS) {
    constexpr int SPk = ((SP + 31) / 32) * 32;
    constexpr int KST = 40;          // K LDS row stride (ushort), 16B-aligned rows
    constexpr int PST = SPk + 8;     // P / Vt row stride
    constexpr int NT = SP / 16;      // 16-wide j tiles
    constexpr int NB = HPB * NT;     // row bands total
    constexpr int HB = 8 / HPB;      // head-blocks per group
    __shared__ ushort KsA[HPB * SP * KST];
    __shared__ ushort VtA[HPB * 32 * PST];
    __shared__ ushort PA [HPB * SP * PST];

    const int tid = threadIdx.x;
    const int g = blockIdx.x / HB;
    const int hbase = (blockIdx.x % HB) * HPB;

    // stage K (frag-row layout) and V^T (transposed)
    for (int idx = tid; idx < HPB * S * 4; idx += 256) {
        int hh = idx / (S * 4); int rem = idx - hh * (S * 4);
        int j = rem >> 2, q = rem & 3;
        const ushort* base = qkv + ((size_t)g * rsG + (size_t)j * rsS) * 768 + (hbase + hh) * 32 + q * 8;
        uint4 kv = *(const uint4*)(base + 256);
        ushort* kd = KsA + hh * (SP * KST) + j * KST + q * 8;
        *(uint2*)kd = make_uint2(kv.x, kv.y);
        *(uint2*)(kd + 4) = make_uint2(kv.z, kv.w);
        uint4 vv = *(const uint4*)(base + 512);
        ushort* vt = VtA + hh * (32 * PST) + j;
        unsigned int uu[4] = {vv.x, vv.y, vv.z, vv.w};
#pragma unroll
        for (int e = 0; e < 4; ++e) {
            vt[(q * 8 + e * 2    ) * PST] = (ushort)(uu[e] & 0xffff);
            vt[(q * 8 + e * 2 + 1) * PST] = (ushort)(uu[e] >> 16);
        }
    }
    // zero V^T k-columns [S, SPk) (avoid 0*garbage=NaN in PV)
    for (int idx = tid; idx < HPB * 32 * (SPk - S); idx += 256) {
        int hh = idx / (32 * (SPk - S)); int rem = idx - hh * (32 * (SPk - S));
        int d = rem / (SPk - S); int c = S + rem - d * (SPk - S);
        VtA[hh * 32 * PST + d * PST + c] = 0;
    }
    // zero P k-columns [SP, SPk)
    if constexpr (SPk > SP) {
        constexpr int PW = SPk - SP;
        for (int idx = tid; idx < HPB * SP * PW; idx += 256) {
            int hh = idx / (SP * PW); int rem = idx - hh * (SP * PW);
            int rrow = rem / PW; int c = SP + rem - rrow * PW;
            PA[hh * SP * PST + rrow * PST + c] = 0;
        }
    }
    __syncthreads();

    const int wv = tid >> 6, lane = tid & 63, fr = lane & 15, hi = lane >> 4;
    for (int band = wv; band < NB; band += 4) {
        const int hh = band / NT, mb = band - (band / NT) * NT;
        const int h = hbase + hh;
        const ushort* Ks = KsA + hh * (SP * KST);
        const ushort* Vt = VtA + hh * (32 * PST);
        ushort* P = PA + hh * (SP * PST);

        int sq = mb * 16 + fr; if (sq > S - 1) sq = S - 1;
        bf16x8 qf = *(const bf16x8*)(qkv + ((size_t)g * rsG + (size_t)sq * rsS) * 768 + h * 32 + hi * 8);
        f32x4 sc[NT];
#pragma unroll
        for (int t = 0; t < NT; ++t) {
            bf16x8 kf = *(const bf16x8*)(Ks + (t * 16 + fr) * KST + hi * 8);
            sc[t] = __builtin_amdgcn_mfma_f32_16x16x32_bf16(qf, kf, f32x4{0.f, 0.f, 0.f, 0.f}, 0, 0, 0);
        }
#pragma unroll
        for (int t = 0; t < NT; ++t) {
            bool valid = (t * 16 + fr) < S;
#pragma unroll
            for (int r = 0; r < 4; ++r)
                sc[t][r] = valid ? sc[t][r] * 0.17677669529663687f : -1e30f;
        }
        // softmax per accumulator row, P -> LDS bf16 (own rows only, no barrier)
#pragma unroll
        for (int r = 0; r < 4; ++r) {
            float m = sc[0][r];
#pragma unroll
            for (int t = 1; t < NT; ++t) m = fmaxf(m, sc[t][r]);
            m = fmaxf(m, __shfl_xor(m, 1)); m = fmaxf(m, __shfl_xor(m, 2));
            m = fmaxf(m, __shfl_xor(m, 4)); m = fmaxf(m, __shfl_xor(m, 8));
            float e[NT]; float sum = 0.f;
#pragma unroll
            for (int t = 0; t < NT; ++t) { e[t] = __expf(sc[t][r] - m); sum += e[t]; }
            sum += __shfl_xor(sum, 1); sum += __shfl_xor(sum, 2);
            sum += __shfl_xor(sum, 4); sum += __shfl_xor(sum, 8);
            float inv = 1.f / sum;
            int row = mb * 16 + hi * 4 + r;
#pragma unroll
            for (int t = 0; t < NT; ++t)
                P[row * PST + t * 16 + fr] = f2bf(e[t] * inv);
        }
        // PV
        f32x4 o0 = {0.f, 0.f, 0.f, 0.f}, o1 = {0.f, 0.f, 0.f, 0.f};
#pragma unroll
        for (int kb = 0; kb < SPk / 32; ++kb) {
            bf16x8 pf = *(const bf16x8*)(P + (mb * 16 + fr) * PST + kb * 32 + hi * 8);
            bf16x8 v0 = *(const bf16x8*)(Vt + fr * PST + kb * 32 + hi * 8);
            bf16x8 v1 = *(const bf16x8*)(Vt + (16 + fr) * PST + kb * 32 + hi * 8);
            o0 = __builtin_amdgcn_mfma_f32_16x16x32_bf16(pf, v0, o0, 0, 0, 0);
            o1 = __builtin_amdgcn_mfma_f32_16x16x32_bf16(pf, v1, o1, 0, 0, 0);
        }
#pragma unroll
        for (int r = 0; r < 4; ++r) {
            int s = mb * 16 + hi * 4 + r;
            if (s < S) {
                size_t ob = ((size_t)g * rsG + (size_t)s * rsS) * 256 + h * 32;
                outb[ob + fr] = f2bf(o0[r]);
                outb[ob + 16 + fr] = f2bf(o1[r]);
            }
        }
    }
}

// ---------------- fused residual + layernorm, f32 out + optional bf16 shadow ----------------
__global__ __launch_bounds__(256)
void addln_kernel(const float* __restrict__ base, const float* __restrict__ delta,
                  const float* __restrict__ gamma, const float* __restrict__ beta,
                  float* __restrict__ out, ushort* __restrict__ obf, int M) {
    int row = blockIdx.x * 4 + (threadIdx.x >> 6);
    int lane = threadIdx.x & 63;
    if (row >= M) return;
    const float* pb = base + (size_t)row * 256;
    const float* pd = delta + (size_t)row * 256;
    float v[4]; float s = 0.f;
#pragma unroll
    for (int i = 0; i < 4; ++i) { int c = lane + i * 64; v[i] = pb[c] + pd[c]; s += v[i]; }
#pragma unroll
    for (int off = 32; off; off >>= 1) s += __shfl_xor(s, off);
    float mean = s * (1.f / 256.f);
    float var = 0.f;
#pragma unroll
    for (int i = 0; i < 4; ++i) { float d = v[i] - mean; var += d * d; }
#pragma unroll
    for (int off = 32; off; off >>= 1) var += __shfl_xor(var, off);
    var *= (1.f / 256.f);
    float rstd = rsqrtf(var + 1e-5f);
#pragma unroll
    for (int i = 0; i < 4; ++i) {
        int c = lane + i * 64;
        float o = (v[i] - mean) * rstd * gamma[c] + beta[c];
        out[(size_t)row * 256 + c] = o;
        if (obf) obf[(size_t)row * 256 + c] = f2bf(o);
    }
}

// ---------------- attention-weight softmax ----------------
__global__ __launch_bounds__(256)
void awsm_kernel(const float* __restrict__ aw, float* __restrict__ awn) {
    int u = blockIdx.x * 256 + threadIdx.x;
    if (u >= NTOK_ * 8) return;
    int row = u >> 3, h = u & 7;
    const float* p = aw + (size_t)row * 128 + h * 16;
    float w[16], m = -1e30f;
#pragma unroll
    for (int i = 0; i < 16; ++i) { w[i] = p[i]; m = fmaxf(m, w[i]); }
    float sum = 0.f;
#pragma unroll
    for (int i = 0; i < 16; ++i) { w[i] = __expf(w[i] - m); sum += w[i]; }
    float inv = 1.f / sum;
    float* o = awn + (size_t)u * 16;
#pragma unroll
    for (int i = 0; i < 16; ++i) o[i] = w[i] * inv;
}

// ---------------- MSDeformAttn bilinear sampling (bf16 value, bf16 out) ----------------
__global__ __launch_bounds__(256)
void msda_kernel(const float* __restrict__ offb, const float* __restrict__ awn,
                 const ushort* __restrict__ val, const float* __restrict__ refp,
                 const int* __restrict__ spatial, const int* __restrict__ lsi,
                 ushort* __restrict__ samp) {
    int unit = blockIdx.x * 16 + (threadIdx.x >> 4);
    int lane = threadIdx.x & 15;
    int h = unit & 7;
    int t = unit >> 3;
    int lq = t % LQ_;
    int b = t / LQ_;
    const float* offp = offb + ((size_t)b * LQ_ + lq) * 256 + h * 32;
    const float* wp = awn + (size_t)unit * 16;
    float acc0 = 0.f, acc1 = 0.f;
#pragma unroll
    for (int lvl = 0; lvl < 4; ++lvl) {
        int H = spatial[lvl * 2], W = spatial[lvl * 2 + 1];
        int st = lsi[lvl];
        float rpx = refp[(((size_t)lq * BS_ + b) * 4 + lvl) * 2 + 0];
        float rpy = refp[(((size_t)lq * BS_ + b) * 4 + lvl) * 2 + 1];
        const ushort* vb = val + ((size_t)b * LEN_MEM_ + st) * 256 + h * 32 + lane * 2;
        float fW = (float)W, fH = (float)H;
#pragma unroll
        for (int p = 0; p < 4; ++p) {
            float ox = offp[(lvl * 4 + p) * 2 + 0];
            float oy = offp[(lvl * 4 + p) * 2 + 1];
            float x = rpx * fW + ox - 0.5f;
            float y = rpy * fH + oy - 0.5f;
            float x0f = floorf(x), y0f = floorf(y);
            float lx = x - x0f, ly = y - y0f;
            int x0 = (int)x0f, y0 = (int)y0f;
            int xc0 = min(max(x0, 0), W - 1), xc1 = min(max(x0 + 1, 0), W - 1);
            int yc0 = min(max(y0, 0), H - 1), yc1 = min(max(y0 + 1, 0), H - 1);
            float vx0 = (x0 >= 0 && x0 < W) ? 1.f : 0.f;
            float vx1 = (x0 >= -1 && x0 + 1 < W) ? 1.f : 0.f;
            float vy0 = (y0 >= 0 && y0 < H) ? 1.f : 0.f;
            float vy1 = (y0 >= -1 && y0 + 1 < H) ? 1.f : 0.f;
            float wpt = wp[lvl * 4 + p];
            float w00 = wpt * (1.f - lx) * (1.f - ly) * vx0 * vy0;
            float w10 = wpt * lx * (1.f - ly) * vx1 * vy0;
            float w01 = wpt * (1.f - lx) * ly * vx0 * vy1;
            float w11 = wpt * lx * ly * vx1 * vy1;
            unsigned int u00 = *(const unsigned int*)(vb + ((size_t)yc0 * W + xc0) * 256);
            unsigned int u10 = *(const unsigned int*)(vb + ((size_t)yc0 * W + xc1) * 256);
            unsigned int u01 = *(const unsigned int*)(vb + ((size_t)yc1 * W + xc0) * 256);
            unsigned int u11 = *(const unsigned int*)(vb + ((size_t)yc1 * W + xc1) * 256);
            acc0 += w00 * bf2f(u00 & 0xffff) + w10 * bf2f(u10 & 0xffff)
                  + w01 * bf2f(u01 & 0xffff) + w11 * bf2f(u11 & 0xffff);
            acc1 += w00 * bf2f(u00 >> 16) + w10 * bf2f(u10 >> 16)
                  + w01 * bf2f(u01 >> 16) + w11 * bf2f(u11 >> 16);
        }
    }
    size_t o = ((size_t)b * LQ_ + lq) * 256 + h * 32 + lane * 2;
    unsigned int pack = (unsigned int)f2bf(acc0) | ((unsigned int)f2bf(acc1) << 16);
    *(unsigned int*)(samp + o) = pack;
}

extern "C" void kernel_launch(void* const* d_in, const int* in_sizes, int n_in,
                              void* d_out, int out_size, void* d_ws, size_t ws_size,
                              hipStream_t stream) {
    const float* tgt     = (const float*)d_in[0];
    const float* pos     = (const float*)d_in[1];
    const float* refp    = (const float*)d_in[2];
    const float* memory  = (const float*)d_in[3];
    const float* w_in_w  = (const float*)d_in[4];
    const float* w_in_b  = (const float*)d_in[5];
    const float* w_out_w = (const float*)d_in[6];
    const float* w_out_b = (const float*)d_in[7];
    const float* a_in_w  = (const float*)d_in[8];
    const float* a_in_b  = (const float*)d_in[9];
    const float* a_out_w = (const float*)d_in[10];
    const float* a_out_b = (const float*)d_in[11];
    const float* off_w   = (const float*)d_in[12];
    const float* off_b   = (const float*)d_in[13];
    const float* aw_w    = (const float*)d_in[14];
    const float* aw_b    = (const float*)d_in[15];
    const float* val_w   = (const float*)d_in[16];
    const float* val_b   = (const float*)d_in[17];
    const float* outp_w  = (const float*)d_in[18];
    const float* outp_b  = (const float*)d_in[19];
    const float* wn_g    = (const float*)d_in[20];
    const float* wn_b    = (const float*)d_in[21];
    const float* an_g    = (const float*)d_in[22];
    const float* an_b    = (const float*)d_in[23];
    const float* n1_g    = (const float*)d_in[24];
    const float* n1_b    = (const float*)d_in[25];
    const float* n2_g    = (const float*)d_in[26];
    const float* n2_b    = (const float*)d_in[27];
    const float* l1_w    = (const float*)d_in[28];
    const float* l1_b    = (const float*)d_in[29];
    const float* l2_w    = (const float*)d_in[30];
    const float* l2_b    = (const float*)d_in[31];
    const int*   spatial = (const int*)d_in[32];
    const int*   lsi     = (const int*)d_in[33];
    const unsigned char* pmask = (const unsigned char*)d_in[34];
    float* out = (float*)d_out;

    // workspace layout
    float*  T      = (float*)d_ws;                 // 3,686,400 f32
    ushort* Tbf    = (ushort*)(T + 3686400);       // 3,686,400
    ushort* B16    = Tbf + 3686400;                // 11,059,200 (QKV bf16)
    ushort* CBbf   = B16 + 11059200;               // 3,686,400
    ushort* VALbf  = CBbf + 3686400;               // 23,046,144
    ushort* SAMPbf = VALbf + 23046144;             // 3,686,400
    ushort* Hbf    = SAMPbf + 3686400;             // 14,745,600
    ushort* WB     = Hbf + 14745600;               // 1,277,952
    float*  OFF    = (float*)(WB + 1277952);       // 3,686,400 f32
    float*  AW     = OFF + 3686400;                // 1,843,200
    float*  AWn    = AW + 1843200;                 // 1,843,200

    ushort* WB_win  = WB + 0;
    ushort* WB_wout = WB + 196608;
    ushort* WB_ain  = WB + 262144;
    ushort* WB_aout = WB + 458752;
    ushort* WB_off  = WB + 524288;
    ushort* WB_aw   = WB + 589824;
    ushort* WB_val  = WB + 622592;
    ushort* WB_outp = WB + 688128;
    ushort* WB_l1   = WB + 753664;
    ushort* WB_l2   = WB + 1015808;

    const int n4 = NTOK_ * 256 / 4;

    // 0. weights -> bf16
    wcvt_kernel<<<dim3(128, 10), 256, 0, stream>>>(
        w_in_w, w_out_w, a_in_w, a_out_w, off_w, aw_w, val_w, outp_w, l1_w, l2_w, WB);
    // 1. T = tgt + pos (+bf16)
    addcvt_kernel<<<n4 / 256, 256, 0, stream>>>(tgt, pos, T, Tbf, n4);
    // 2. QKV (within-group), bf16 out
    gemm_kernel<0, false, false, true><<<dim3(113, 6), 256, 0, stream>>>(
        Tbf, WB_win, w_in_b, B16, NTOK_, 768, 256, nullptr);
    // 3. MFMA attention over nk=18: rows = g*18 + s, 4 heads/block
    mattn_kernel<18, 32, 4><<<800 * 2, 256, 0, stream>>>(B16, CBbf, 18, 1);
    // 4. out projection
    gemm_kernel<0, false, false, false><<<dim3(113, 2), 256, 0, stream>>>(
        CBbf, WB_wout, w_out_b, OFF, NTOK_, 256, 256, nullptr);
    // 5. T = LN(T+OFF, wn)
    addln_kernel<<<NTOK_ / 4, 256, 0, stream>>>(T, OFF, wn_g, wn_b, T, Tbf, NTOK_);
    // 6. QKV (across-group), bf16 out
    gemm_kernel<0, false, false, true><<<dim3(113, 6), 256, 0, stream>>>(
        Tbf, WB_ain, a_in_b, B16, NTOK_, 768, 256, nullptr);
    // 7. MFMA attention over nq=100: rows = g + s*144, 1 head/block
    mattn_kernel<100, 112, 1><<<144 * 8, 256, 0, stream>>>(B16, CBbf, 1, 144);
    // 8. out projection
    gemm_kernel<0, false, false, false><<<dim3(113, 2), 256, 0, stream>>>(
        CBbf, WB_aout, a_out_b, OFF, NTOK_, 256, 256, nullptr);
    // 9. T = LN(T+OFF, an)
    addln_kernel<<<NTOK_ / 4, 256, 0, stream>>>(T, OFF, an_g, an_b, T, Tbf, NTOK_);
    // 10. T += pos (t3)
    addcvt_kernel<<<n4 / 256, 256, 0, stream>>>(T, pos, T, Tbf, n4);
    // 11. value projection (f32 memory in, bf16 out, masked) -> (b,m) order
    gemm_kernel<1, false, true, true><<<dim3(704, 2), 256, 0, stream>>>(
        memory, WB_val, val_b, VALbf, 90024, 256, 256, pmask);
    // 12. offsets projection (rows (b,lq))
    gemm_kernel<2, false, false, false><<<dim3(113, 2), 256, 0, stream>>>(
        Tbf, WB_off, off_b, OFF, NTOK_, 256, 256, nullptr);
    // 13. attention-weight logits
    gemm_kernel<2, false, false, false><<<dim3(113, 1), 256, 0, stream>>>(
        Tbf, WB_aw, aw_b, AW, NTOK_, 128, 256, nullptr);
    // 14. softmax over 16 points
    awsm_kernel<<<(NTOK_ * 8 + 255) / 256, 256, 0, stream>>>(AW, AWn);
    // 15. bilinear sampling
    msda_kernel<<<NTOK_ * 8 / 16, 256, 0, stream>>>(OFF, AWn, VALbf, refp, spatial, lsi, SAMPbf);
    // 16. msda output projection (rows back to (q,b,k))
    gemm_kernel<3, false, false, false><<<dim3(113, 2), 256, 0, stream>>>(
        SAMPbf, WB_outp, outp_b, OFF, NTOK_, 256, 256, nullptr);
    // 17. T = LN(T+OFF, n1)
    addln_kernel<<<NTOK_ / 4, 256, 0, stream>>>(T, OFF, n1_g, n1_b, T, Tbf, NTOK_);
    // 18. FFN up + ReLU (bf16 out)
    gemm_kernel<0, true, false, true><<<dim3(113, 8), 256, 0, stream>>>(
        Tbf, WB_l1, l1_b, Hbf, NTOK_, 1024, 256, nullptr);
    // 19. FFN down
    gemm_kernel<0, false, false, false><<<dim3(113, 2), 256, 0, stream>>>(
        Hbf, WB_l2, l2_b, OFF, NTOK_, 256, 1024, nullptr);
    // 20. out = LN(T+OFF, n2)
    addln_kernel<<<NTOK_ / 4, 256, 0, stream>>>(T, OFF, n2_g, n2_b, out, nullptr, NTOK_);
}

// Round 5
// 361.138 us; speedup vs baseline: 3.9590x; 1.0267x over previous
//
#include <hip/hip_runtime.h>
#include <math.h>

#define NH_ 8
#define D_ 256
#define NK_ 18
#define NQ_ 100
#define BS_ 8
#define LQ_ 1800          // NQ*NK
#define LEN_MEM_ 11253
#define NTOK_ 14400       // NQ*BS*NK

typedef short bf16x8 __attribute__((ext_vector_type(8)));
typedef float f32x4 __attribute__((ext_vector_type(4)));
typedef unsigned short ushort;

__device__ inline ushort f2bf(float f) {
    unsigned int u = __builtin_bit_cast(unsigned int, f);
    unsigned int r = (u + 0x7fffu + ((u >> 16) & 1u)) >> 16;
    return (ushort)r;
}
__device__ inline float bf2f(unsigned int u16) {
    unsigned int i = u16 << 16;
    return __builtin_bit_cast(float, i);
}
__device__ inline int packbf2(float a, float b) {
    return (int)f2bf(a) | ((int)f2bf(b) << 16);
}

// ---------------- weight convert: 10 f32 tensors -> packed bf16 arena ----------------
__global__ __launch_bounds__(256)
void wcvt_kernel(const float* s0, const float* s1, const float* s2, const float* s3,
                 const float* s4, const float* s5, const float* s6, const float* s7,
                 const float* s8, const float* s9, ushort* dst) {
    const int sizes[10] = {196608,65536,196608,65536,65536,32768,65536,65536,262144,262144};
    const int offs[10]  = {0,196608,262144,458752,524288,589824,622592,688128,753664,1015808};
    int ti = blockIdx.y;
    const float* s;
    switch (ti) {
        case 0: s = s0; break; case 1: s = s1; break; case 2: s = s2; break;
        case 3: s = s3; break; case 4: s = s4; break; case 5: s = s5; break;
        case 6: s = s6; break; case 7: s = s7; break; case 8: s = s8; break;
        default: s = s9; break;
    }
    int n = sizes[ti];
    int i = (blockIdx.x * 256 + threadIdx.x) * 8;
    if (i >= n) return;
    ushort* d = dst + offs[ti] + i;
    float4 f0 = *(const float4*)(s + i);
    float4 f1 = *(const float4*)(s + i + 4);
    int4 val;
    val.x = packbf2(f0.x, f0.y);
    val.y = packbf2(f0.z, f0.w);
    val.z = packbf2(f1.x, f1.y);
    val.w = packbf2(f1.z, f1.w);
    *(int4*)d = val;
}

// ---------------- c = a + b, f32 out + bf16 shadow ----------------
__global__ __launch_bounds__(256)
void addcvt_kernel(const float* __restrict__ a, const float* __restrict__ b,
                   float* __restrict__ c, ushort* __restrict__ cbf, int n4) {
    int i = blockIdx.x * blockDim.x + threadIdx.x;
    if (i >= n4) return;
    float4 av = ((const float4*)a)[i];
    float4 bv = ((const float4*)b)[i];
    float4 cv;
    cv.x = av.x + bv.x; cv.y = av.y + bv.y; cv.z = av.z + bv.z; cv.w = av.w + bv.w;
    ((float4*)c)[i] = cv;
    uint2 p;
    p.x = (unsigned int)packbf2(cv.x, cv.y);
    p.y = (unsigned int)packbf2(cv.z, cv.w);
    *(uint2*)(cbf + (size_t)i * 4) = p;
}

// ---------------- MFMA bf16 GEMM: C[m,n] = A[m,:] . W[n,:] + bias[n] ----------------
// BK = 64, 128x128 tile, 4 waves.
// MODE 0: identity rows.
// MODE 1: value projection. rows identity ((m,b) layout); zero by mask[(gm&7)*LEN_MEM + gm>>3].
// MODE 2: input row permute (q,b,k) -> output rows in (b,lq) order.
// MODE 3: input rows (b,lq), output rows (q,b,k).
template<int MODE, bool RELU, bool A_F32, bool OUT_BF16>
__global__ __launch_bounds__(256)
void gemm_kernel(const void* __restrict__ Av, const ushort* __restrict__ W,
                 const float* __restrict__ bias, void* __restrict__ Cv,
                 int M, int N, int K, const unsigned char* __restrict__ mask) {
    constexpr int AST = 72;           // LDS row stride (ushorts)
    __shared__ ushort As[128 * AST];
    __shared__ ushort Bs[128 * AST];
    const int m0 = blockIdx.x * 128, n0 = blockIdx.y * 128;
    const int tid = threadIdx.x;
    const int w = tid >> 6, lane = tid & 63;
    const int wr = w >> 1, wc = w & 1;
    const int fr = lane & 15, hi = lane >> 4;
    f32x4 acc[4][4];
#pragma unroll
    for (int i = 0; i < 4; ++i)
#pragma unroll
        for (int j = 0; j < 4; ++j) acc[i][j] = f32x4{0.f, 0.f, 0.f, 0.f};

    const int srow = tid >> 1, shalf = tid & 1;   // each thread stages 64B of one row-half
    long arow = 0;
    const bool avalid = (m0 + srow) < M;
    {
        int gr = m0 + srow;
        if (gr >= M) gr = M - 1;
        if (MODE == 2) {
            int b = gr / LQ_; int lq = gr - b * LQ_;
            int q = lq / NK_; int kk = lq - q * NK_;
            arow = (long)q * (BS_ * NK_) + b * NK_ + kk;
        } else {
            arow = gr;
        }
    }

    for (int k0 = 0; k0 < K; k0 += 64) {
        ushort* ad = As + srow * AST + shalf * 32;
        if (avalid) {
            if (A_F32) {
                const float* ap = (const float*)Av + arow * (long)K + k0 + shalf * 32;
#pragma unroll
                for (int i = 0; i < 4; ++i) {
                    float4 f0 = *(const float4*)(ap + i * 8);
                    float4 f1 = *(const float4*)(ap + i * 8 + 4);
                    int4 v;
                    v.x = packbf2(f0.x, f0.y); v.y = packbf2(f0.z, f0.w);
                    v.z = packbf2(f1.x, f1.y); v.w = packbf2(f1.z, f1.w);
                    *(int4*)(ad + i * 8) = v;
                }
            } else {
                const ushort* ap = (const ushort*)Av + arow * (long)K + k0 + shalf * 32;
#pragma unroll
                for (int i = 0; i < 4; ++i) *(int4*)(ad + i * 8) = *(const int4*)(ap + i * 8);
            }
        } else {
            int4 z = make_int4(0, 0, 0, 0);
#pragma unroll
            for (int i = 0; i < 4; ++i) *(int4*)(ad + i * 8) = z;
        }
        {
            const ushort* wp = W + (long)(n0 + srow) * K + k0 + shalf * 32;
            ushort* bd = Bs + srow * AST + shalf * 32;
#pragma unroll
            for (int i = 0; i < 4; ++i) *(int4*)(bd + i * 8) = *(const int4*)(wp + i * 8);
        }
        __syncthreads();
#pragma unroll
        for (int kb = 0; kb < 2; ++kb) {
            bf16x8 af[4], bfr[4];
#pragma unroll
            for (int i = 0; i < 4; ++i)
                af[i] = *(const bf16x8*)(As + (wr * 64 + i * 16 + fr) * AST + kb * 32 + hi * 8);
#pragma unroll
            for (int j = 0; j < 4; ++j)
                bfr[j] = *(const bf16x8*)(Bs + (wc * 64 + j * 16 + fr) * AST + kb * 32 + hi * 8);
#pragma unroll
            for (int i = 0; i < 4; ++i)
#pragma unroll
                for (int j = 0; j < 4; ++j)
                    acc[i][j] = __builtin_amdgcn_mfma_f32_16x16x32_bf16(af[i], bfr[j], acc[i][j], 0, 0, 0);
        }
        __syncthreads();
    }

#pragma unroll
    for (int i = 0; i < 4; ++i) {
#pragma unroll
        for (int r = 0; r < 4; ++r) {
            int gm = m0 + wr * 64 + i * 16 + hi * 4 + r;
            if (gm >= M) continue;
            long orow = gm;
            bool zero = false;
            if (MODE == 1) {
                if (mask && mask[(size_t)(gm & 7) * LEN_MEM_ + (gm >> 3)]) zero = true;
            } else if (MODE == 3) {
                int b = gm / LQ_; int lq = gm - b * LQ_;
                int q = lq / NK_; int kk = lq - q * NK_;
                orow = (long)q * (BS_ * NK_) + b * NK_ + kk;
            }
#pragma unroll
            for (int j = 0; j < 4; ++j) {
                int gn = n0 + wc * 64 + j * 16 + fr;
                float v = acc[i][j][r] + bias[gn];
                if (RELU) v = fmaxf(v, 0.f);
                if (zero) v = 0.f;
                if (OUT_BF16) ((ushort*)Cv)[orow * (long)N + gn] = f2bf(v);
                else ((float*)Cv)[orow * (long)N + gn] = v;
            }
        }
    }
}

// ---------------- MFMA multi-head attention over small sequences ----------------
template<int S, int SP, int HPB>
__global__ __launch_bounds__(256)
void mattn_kernel(const ushort* __restrict__ qkv, ushort* __restrict__ outb,
                  int rsG, int rsS) {
    constexpr int SPk = ((SP + 31) / 32) * 32;
    constexpr int KST = 40;
    constexpr int PST = SPk + 8;
    constexpr int NT = SP / 16;
    constexpr int NB = HPB * NT;
    constexpr int HB = 8 / HPB;
    __shared__ ushort KsA[HPB * SP * KST];
    __shared__ ushort VtA[HPB * 32 * PST];
    __shared__ ushort PA [HPB * SP * PST];

    const int tid = threadIdx.x;
    const int g = blockIdx.x / HB;
    const int hbase = (blockIdx.x % HB) * HPB;

    for (int idx = tid; idx < HPB * S * 4; idx += 256) {
        int hh = idx / (S * 4); int rem = idx - hh * (S * 4);
        int j = rem >> 2, q = rem & 3;
        const ushort* base = qkv + ((size_t)g * rsG + (size_t)j * rsS) * 768 + (hbase + hh) * 32 + q * 8;
        uint4 kv = *(const uint4*)(base + 256);
        ushort* kd = KsA + hh * (SP * KST) + j * KST + q * 8;
        *(uint2*)kd = make_uint2(kv.x, kv.y);
        *(uint2*)(kd + 4) = make_uint2(kv.z, kv.w);
        uint4 vv = *(const uint4*)(base + 512);
        ushort* vt = VtA + hh * (32 * PST) + j;
        unsigned int uu[4] = {vv.x, vv.y, vv.z, vv.w};
#pragma unroll
        for (int e = 0; e < 4; ++e) {
            vt[(q * 8 + e * 2    ) * PST] = (ushort)(uu[e] & 0xffff);
            vt[(q * 8 + e * 2 + 1) * PST] = (ushort)(uu[e] >> 16);
        }
    }
    for (int idx = tid; idx < HPB * 32 * (SPk - S); idx += 256) {
        int hh = idx / (32 * (SPk - S)); int rem = idx - hh * (32 * (SPk - S));
        int d = rem / (SPk - S); int c = S + rem - d * (SPk - S);
        VtA[hh * 32 * PST + d * PST + c] = 0;
    }
    if constexpr (SPk > SP) {
        constexpr int PW = SPk - SP;
        for (int idx = tid; idx < HPB * SP * PW; idx += 256) {
            int hh = idx / (SP * PW); int rem = idx - hh * (SP * PW);
            int rrow = rem / PW; int c = SP + rem - rrow * PW;
            PA[hh * SP * PST + rrow * PST + c] = 0;
        }
    }
    __syncthreads();

    const int wv = tid >> 6, lane = tid & 63, fr = lane & 15, hi = lane >> 4;
    for (int band = wv; band < NB; band += 4) {
        const int hh = band / NT, mb = band - (band / NT) * NT;
        const int h = hbase + hh;
        const ushort* Ks = KsA + hh * (SP * KST);
        const ushort* Vt = VtA + hh * (32 * PST);
        ushort* P = PA + hh * (SP * PST);

        int sq = mb * 16 + fr; if (sq > S - 1) sq = S - 1;
        bf16x8 qf = *(const bf16x8*)(qkv + ((size_t)g * rsG + (size_t)sq * rsS) * 768 + h * 32 + hi * 8);
        f32x4 sc[NT];
#pragma unroll
        for (int t = 0; t < NT; ++t) {
            bf16x8 kf = *(const bf16x8*)(Ks + (t * 16 + fr) * KST + hi * 8);
            sc[t] = __builtin_amdgcn_mfma_f32_16x16x32_bf16(qf, kf, f32x4{0.f, 0.f, 0.f, 0.f}, 0, 0, 0);
        }
#pragma unroll
        for (int t = 0; t < NT; ++t) {
            bool valid = (t * 16 + fr) < S;
#pragma unroll
            for (int r = 0; r < 4; ++r)
                sc[t][r] = valid ? sc[t][r] * 0.17677669529663687f : -1e30f;
        }
#pragma unroll
        for (int r = 0; r < 4; ++r) {
            float m = sc[0][r];
#pragma unroll
            for (int t = 1; t < NT; ++t) m = fmaxf(m, sc[t][r]);
            m = fmaxf(m, __shfl_xor(m, 1)); m = fmaxf(m, __shfl_xor(m, 2));
            m = fmaxf(m, __shfl_xor(m, 4)); m = fmaxf(m, __shfl_xor(m, 8));
            float e[NT]; float sum = 0.f;
#pragma unroll
            for (int t = 0; t < NT; ++t) { e[t] = __expf(sc[t][r] - m); sum += e[t]; }
            sum += __shfl_xor(sum, 1); sum += __shfl_xor(sum, 2);
            sum += __shfl_xor(sum, 4); sum += __shfl_xor(sum, 8);
            float inv = 1.f / sum;
            int row = mb * 16 + hi * 4 + r;
#pragma unroll
            for (int t = 0; t < NT; ++t)
                P[row * PST + t * 16 + fr] = f2bf(e[t] * inv);
        }
        f32x4 o0 = {0.f, 0.f, 0.f, 0.f}, o1 = {0.f, 0.f, 0.f, 0.f};
#pragma unroll
        for (int kb = 0; kb < SPk / 32; ++kb) {
            bf16x8 pf = *(const bf16x8*)(P + (mb * 16 + fr) * PST + kb * 32 + hi * 8);
            bf16x8 v0 = *(const bf16x8*)(Vt + fr * PST + kb * 32 + hi * 8);
            bf16x8 v1 = *(const bf16x8*)(Vt + (16 + fr) * PST + kb * 32 + hi * 8);
            o0 = __builtin_amdgcn_mfma_f32_16x16x32_bf16(pf, v0, o0, 0, 0, 0);
            o1 = __builtin_amdgcn_mfma_f32_16x16x32_bf16(pf, v1, o1, 0, 0, 0);
        }
#pragma unroll
        for (int r = 0; r < 4; ++r) {
            int s = mb * 16 + hi * 4 + r;
            if (s < S) {
                size_t ob = ((size_t)g * rsG + (size_t)s * rsS) * 256 + h * 32;
                outb[ob + fr] = f2bf(o0[r]);
                outb[ob + 16 + fr] = f2bf(o1[r]);
            }
        }
    }
}

// ---------------- fused residual + layernorm (+ optional pos add), f32 out + bf16 shadow ----------------
__global__ __launch_bounds__(256)
void addln_kernel(const float* __restrict__ base, const float* __restrict__ delta,
                  const float* __restrict__ gamma, const float* __restrict__ beta,
                  const float* __restrict__ pos,
                  float* __restrict__ out, ushort* __restrict__ obf, int M) {
    int row = blockIdx.x * 4 + (threadIdx.x >> 6);
    int lane = threadIdx.x & 63;
    if (row >= M) return;
    const float* pb = base + (size_t)row * 256;
    const float* pd = delta + (size_t)row * 256;
    float v[4]; float s = 0.f;
#pragma unroll
    for (int i = 0; i < 4; ++i) { int c = lane + i * 64; v[i] = pb[c] + pd[c]; s += v[i]; }
#pragma unroll
    for (int off = 32; off; off >>= 1) s += __shfl_xor(s, off);
    float mean = s * (1.f / 256.f);
    float var = 0.f;
#pragma unroll
    for (int i = 0; i < 4; ++i) { float d = v[i] - mean; var += d * d; }
#pragma unroll
    for (int off = 32; off; off >>= 1) var += __shfl_xor(var, off);
    var *= (1.f / 256.f);
    float rstd = rsqrtf(var + 1e-5f);
#pragma unroll
    for (int i = 0; i < 4; ++i) {
        int c = lane + i * 64;
        float o = (v[i] - mean) * rstd * gamma[c] + beta[c];
        if (pos) o += pos[(size_t)row * 256 + c];
        out[(size_t)row * 256 + c] = o;
        if (obf) obf[(size_t)row * 256 + c] = f2bf(o);
    }
}

// ---------------- MSDeformAttn: fused 16-pt softmax + bilinear sampling ----------------
// value: (LEN_MEM, BS, NH, 32) bf16 i.e. row (m*8+b). 16 lanes per (b,lq,h) unit.
__global__ __launch_bounds__(256)
void msda_kernel(const float* __restrict__ offb, const float* __restrict__ aw,
                 const ushort* __restrict__ val, const float* __restrict__ refp,
                 const int* __restrict__ spatial, const int* __restrict__ lsi,
                 ushort* __restrict__ samp) {
    int unit = blockIdx.x * 16 + (threadIdx.x >> 4);
    int lane = threadIdx.x & 15;
    int lbase = (threadIdx.x & 63) & 48;
    int h = unit & 7;
    int t = unit >> 3;
    int lq = t % LQ_;
    int b = t / LQ_;

    // fused softmax over the 16 points: lane p owns logit p
    float logit = aw[((size_t)b * LQ_ + lq) * 128 + h * 16 + lane];
    float m = logit;
    m = fmaxf(m, __shfl_xor(m, 1)); m = fmaxf(m, __shfl_xor(m, 2));
    m = fmaxf(m, __shfl_xor(m, 4)); m = fmaxf(m, __shfl_xor(m, 8));
    float e = __expf(logit - m);
    float sum = e;
    sum += __shfl_xor(sum, 1); sum += __shfl_xor(sum, 2);
    sum += __shfl_xor(sum, 4); sum += __shfl_xor(sum, 8);
    float wnorm = e / sum;

    // per-lane offset pair (lane p owns point p's (ox,oy))
    const float* offp = offb + ((size_t)b * LQ_ + lq) * 256 + h * 32;
    float2 myoff = ((const float2*)offp)[lane];

    float acc0 = 0.f, acc1 = 0.f;
#pragma unroll
    for (int lvl = 0; lvl < 4; ++lvl) {
        int H = spatial[lvl * 2], W = spatial[lvl * 2 + 1];
        int st = lsi[lvl];
        float rpx = refp[(((size_t)lq * BS_ + b) * 4 + lvl) * 2 + 0];
        float rpy = refp[(((size_t)lq * BS_ + b) * 4 + lvl) * 2 + 1];
        const ushort* vb = val + ((size_t)st * 8 + b) * 256 + h * 32 + lane * 2;
        float fW = (float)W, fH = (float)H;
#pragma unroll
        for (int p = 0; p < 4; ++p) {
            int pi = lvl * 4 + p;
            float ox = __shfl(myoff.x, lbase + pi);
            float oy = __shfl(myoff.y, lbase + pi);
            float wpt = __shfl(wnorm, lbase + pi);
            float x = rpx * fW + ox - 0.5f;
            float y = rpy * fH + oy - 0.5f;
            float x0f = floorf(x), y0f = floorf(y);
            float lx = x - x0f, ly = y - y0f;
            int x0 = (int)x0f, y0 = (int)y0f;
            int xc0 = min(max(x0, 0), W - 1), xc1 = min(max(x0 + 1, 0), W - 1);
            int yc0 = min(max(y0, 0), H - 1), yc1 = min(max(y0 + 1, 0), H - 1);
            float vx0 = (x0 >= 0 && x0 < W) ? 1.f : 0.f;
            float vx1 = (x0 >= -1 && x0 + 1 < W) ? 1.f : 0.f;
            float vy0 = (y0 >= 0 && y0 < H) ? 1.f : 0.f;
            float vy1 = (y0 >= -1 && y0 + 1 < H) ? 1.f : 0.f;
            float w00 = wpt * (1.f - lx) * (1.f - ly) * vx0 * vy0;
            float w10 = wpt * lx * (1.f - ly) * vx1 * vy0;
            float w01 = wpt * (1.f - lx) * ly * vx0 * vy1;
            float w11 = wpt * lx * ly * vx1 * vy1;
            unsigned int u00 = *(const unsigned int*)(vb + ((size_t)(yc0 * W + xc0) * 8) * 256);
            unsigned int u10 = *(const unsigned int*)(vb + ((size_t)(yc0 * W + xc1) * 8) * 256);
            unsigned int u01 = *(const unsigned int*)(vb + ((size_t)(yc1 * W + xc0) * 8) * 256);
            unsigned int u11 = *(const unsigned int*)(vb + ((size_t)(yc1 * W + xc1) * 8) * 256);
            acc0 += w00 * bf2f(u00 & 0xffff) + w10 * bf2f(u10 & 0xffff)
                  + w01 * bf2f(u01 & 0xffff) + w11 * bf2f(u11 & 0xffff);
            acc1 += w00 * bf2f(u00 >> 16) + w10 * bf2f(u10 >> 16)
                  + w01 * bf2f(u01 >> 16) + w11 * bf2f(u11 >> 16);
        }
    }
    size_t o = ((size_t)b * LQ_ + lq) * 256 + h * 32 + lane * 2;
    *(unsigned int*)(samp + o) = (unsigned int)packbf2(acc0, acc1);
}

extern "C" void kernel_launch(void* const* d_in, const int* in_sizes, int n_in,
                              void* d_out, int out_size, void* d_ws, size_t ws_size,
                              hipStream_t stream) {
    const float* tgt     = (const float*)d_in[0];
    const float* pos     = (const float*)d_in[1];
    const float* refp    = (const float*)d_in[2];
    const float* memory  = (const float*)d_in[3];
    const float* w_in_w  = (const float*)d_in[4];
    const float* w_in_b  = (const float*)d_in[5];
    const float* w_out_w = (const float*)d_in[6];
    const float* w_out_b = (const float*)d_in[7];
    const float* a_in_w  = (const float*)d_in[8];
    const float* a_in_b  = (const float*)d_in[9];
    const float* a_out_w = (const float*)d_in[10];
    const float* a_out_b = (const float*)d_in[11];
    const float* off_w   = (const float*)d_in[12];
    const float* off_b   = (const float*)d_in[13];
    const float* aw_w    = (const float*)d_in[14];
    const float* aw_b    = (const float*)d_in[15];
    const float* val_w   = (const float*)d_in[16];
    const float* val_b   = (const float*)d_in[17];
    const float* outp_w  = (const float*)d_in[18];
    const float* outp_b  = (const float*)d_in[19];
    const float* wn_g    = (const float*)d_in[20];
    const float* wn_b    = (const float*)d_in[21];
    const float* an_g    = (const float*)d_in[22];
    const float* an_b    = (const float*)d_in[23];
    const float* n1_g    = (const float*)d_in[24];
    const float* n1_b    = (const float*)d_in[25];
    const float* n2_g    = (const float*)d_in[26];
    const float* n2_b    = (const float*)d_in[27];
    const float* l1_w    = (const float*)d_in[28];
    const float* l1_b    = (const float*)d_in[29];
    const float* l2_w    = (const float*)d_in[30];
    const float* l2_b    = (const float*)d_in[31];
    const int*   spatial = (const int*)d_in[32];
    const int*   lsi     = (const int*)d_in[33];
    const unsigned char* pmask = (const unsigned char*)d_in[34];
    float* out = (float*)d_out;

    // workspace layout
    float*  T      = (float*)d_ws;                 // 3,686,400 f32
    ushort* Tbf    = (ushort*)(T + 3686400);       // 3,686,400
    ushort* B16    = Tbf + 3686400;                // 11,059,200 (QKV bf16)
    ushort* CBbf   = B16 + 11059200;               // 3,686,400
    ushort* VALbf  = CBbf + 3686400;               // 23,046,144  (m,b) layout
    ushort* SAMPbf = VALbf + 23046144;             // 3,686,400
    ushort* Hbf    = SAMPbf + 3686400;             // 14,745,600
    ushort* WB     = Hbf + 14745600;               // 1,277,952
    float*  OFF    = (float*)(WB + 1277952);       // 3,686,400 f32
    float*  AW     = OFF + 3686400;                // 1,843,200

    ushort* WB_win  = WB + 0;
    ushort* WB_wout = WB + 196608;
    ushort* WB_ain  = WB + 262144;
    ushort* WB_aout = WB + 458752;
    ushort* WB_off  = WB + 524288;
    ushort* WB_aw   = WB + 589824;
    ushort* WB_val  = WB + 622592;
    ushort* WB_outp = WB + 688128;
    ushort* WB_l1   = WB + 753664;
    ushort* WB_l2   = WB + 1015808;

    const int n4 = NTOK_ * 256 / 4;

    // 0. weights -> bf16
    wcvt_kernel<<<dim3(128, 10), 256, 0, stream>>>(
        w_in_w, w_out_w, a_in_w, a_out_w, off_w, aw_w, val_w, outp_w, l1_w, l2_w, WB);
    // 1. T = tgt + pos (+bf16)
    addcvt_kernel<<<n4 / 256, 256, 0, stream>>>(tgt, pos, T, Tbf, n4);
    // 2. QKV (within-group), bf16 out
    gemm_kernel<0, false, false, true><<<dim3(113, 6), 256, 0, stream>>>(
        Tbf, WB_win, w_in_b, B16, NTOK_, 768, 256, nullptr);
    // 3. MFMA attention over nk=18
    mattn_kernel<18, 32, 4><<<800 * 2, 256, 0, stream>>>(B16, CBbf, 18, 1);
    // 4. out projection
    gemm_kernel<0, false, false, false><<<dim3(113, 2), 256, 0, stream>>>(
        CBbf, WB_wout, w_out_b, OFF, NTOK_, 256, 256, nullptr);
    // 5. T = LN(T+OFF, wn)
    addln_kernel<<<NTOK_ / 4, 256, 0, stream>>>(T, OFF, wn_g, wn_b, nullptr, T, Tbf, NTOK_);
    // 6. QKV (across-group), bf16 out
    gemm_kernel<0, false, false, true><<<dim3(113, 6), 256, 0, stream>>>(
        Tbf, WB_ain, a_in_b, B16, NTOK_, 768, 256, nullptr);
    // 7. MFMA attention over nq=100
    mattn_kernel<100, 112, 1><<<144 * 8, 256, 0, stream>>>(B16, CBbf, 1, 144);
    // 8. out projection
    gemm_kernel<0, false, false, false><<<dim3(113, 2), 256, 0, stream>>>(
        CBbf, WB_aout, a_out_b, OFF, NTOK_, 256, 256, nullptr);
    // 9+10. T = LN(T+OFF, an) + pos (fused)
    addln_kernel<<<NTOK_ / 4, 256, 0, stream>>>(T, OFF, an_g, an_b, pos, T, Tbf, NTOK_);
    // 11. value projection -> (m,b) layout, coalesced identity rows, masked
    gemm_kernel<1, false, true, true><<<dim3(704, 2), 256, 0, stream>>>(
        memory, WB_val, val_b, VALbf, 90024, 256, 256, pmask);
    // 12. offsets projection (rows (b,lq))
    gemm_kernel<2, false, false, false><<<dim3(113, 2), 256, 0, stream>>>(
        Tbf, WB_off, off_b, OFF, NTOK_, 256, 256, nullptr);
    // 13. attention-weight logits (rows (b,lq))
    gemm_kernel<2, false, false, false><<<dim3(113, 1), 256, 0, stream>>>(
        Tbf, WB_aw, aw_b, AW, NTOK_, 128, 256, nullptr);
    // 14. fused softmax + bilinear sampling
    msda_kernel<<<NTOK_ * 8 / 16, 256, 0, stream>>>(OFF, AW, VALbf, refp, spatial, lsi, SAMPbf);
    // 15. msda output projection (rows back to (q,b,k))
    gemm_kernel<3, false, false, false><<<dim3(113, 2), 256, 0, stream>>>(
        SAMPbf, WB_outp, outp_b, OFF, NTOK_, 256, 256, nullptr);
    // 16. T = LN(T+OFF, n1)
    addln_kernel<<<NTOK_ / 4, 256, 0, stream>>>(T, OFF, n1_g, n1_b, nullptr, T, Tbf, NTOK_);
    // 17. FFN up + ReLU (bf16 out)
    gemm_kernel<0, true, false, true><<<dim3(113, 8), 256, 0, stream>>>(
        Tbf, WB_l1, l1_b, Hbf, NTOK_, 1024, 256, nullptr);
    // 18. FFN down
    gemm_kernel<0, false, false, false><<<dim3(113, 2), 256, 0, stream>>>(
        Hbf, WB_l2, l2_b, OFF, NTOK_, 256, 1024, nullptr);
    // 19. out = LN(T+OFF, n2)
    addln_kernel<<<NTOK_ / 4, 256, 0, stream>>>(T, OFF, n2_g, n2_b, nullptr, out, nullptr, NTOK_);
}